// Round 4
// baseline (375.293 us; speedup 1.0000x reference)
//
#include <hip/hip_runtime.h>

// Problem constants
#define BB 16
#define NN 512
#define HH 128
#define SB 32   // slabs (blocks) per batch
#define RB 16   // rows per slab

#define SCOPE_AGENT __HIP_MEMORY_SCOPE_AGENT

// ---------------------------------------------------------------- embed ----
__global__ __launch_bounds__(256) void embed_kernel(
    const float* __restrict__ pts, const float* __restrict__ Wemb,
    const float* __restrict__ bemb, float* __restrict__ x)
{
  int idx = blockIdx.x * 256 + threadIdx.x;   // 0 .. B*N*H
  int h  = idx & (HH - 1);
  int bn = idx >> 7;
  float p0 = pts[bn * 2 + 0], p1 = pts[bn * 2 + 1];
  x[idx] = fmaf(p0, Wemb[h], fmaf(p1, Wemb[HH + h], bemb[h]));
}

// ----------------------------------------------------------------- GEMM ----
// MODE 0: plain (bmm).  MODE 1: +bias, relu (B shared weights).
// MODE 2: logits epilogue (diag mask, 10*tanh, gumbel, /T).
// EXPA: A element = exp(-raw).  TRANSB: B[k][n] = Braw[n][k].
constexpr int BMt = 64, BNt = 64, BKt = 32;

template <int MODE, bool EXPA, bool TRANSB, int Mdim, int Ndim, int Kdim>
__global__ __launch_bounds__(256) void gemm_kernel(
    const float* __restrict__ Ag, const float* __restrict__ Bg,
    const float* __restrict__ bias, const float* __restrict__ noise,
    float* __restrict__ Cg)
{
  constexpr int TMn = Mdim / BMt, TNn = Ndim / BNt;
  const int bid = blockIdx.x;
  const int tn  = bid % TNn;
  const int tmi = (bid / TNn) % TMn;
  const int b   = bid / (TNn * TMn);
  const int tid = threadIdx.x;
  const int row0 = tmi * BMt, col0 = tn * BNt;

  __shared__ float Al[BKt][BMt + 4];
  __shared__ float Bl[BKt][BNt + 4];

  const float* Ab = Ag + (size_t)b * Mdim * Kdim;
  const size_t bstrideB = (MODE == 1) ? (size_t)0 : (size_t)Kdim * Ndim;
  const float* Bb = Bg + (size_t)b * bstrideB;

  const int rowr = (tid >> 4) * 4;
  const int colr = (tid & 15) * 4;

  float acc[4][4] = {};

  for (int k0 = 0; k0 < Kdim; k0 += BKt) {
    {
      int r = tid >> 3, kq = (tid & 7) * 4;
      #pragma unroll
      for (int rr = 0; rr < BMt; rr += 32) {
        float4 v = *reinterpret_cast<const float4*>(
            &Ab[(size_t)(row0 + r + rr) * Kdim + k0 + kq]);
        if (EXPA) {
          v.x = __expf(-v.x); v.y = __expf(-v.y);
          v.z = __expf(-v.z); v.w = __expf(-v.w);
        }
        Al[kq + 0][r + rr] = v.x; Al[kq + 1][r + rr] = v.y;
        Al[kq + 2][r + rr] = v.z; Al[kq + 3][r + rr] = v.w;
      }
    }
    if (!TRANSB) {
      int kk = tid >> 4, nc = (tid & 15) * 4;
      #pragma unroll
      for (int kr = 0; kr < BKt; kr += 16) {
        float4 v = *reinterpret_cast<const float4*>(
            &Bb[(size_t)(k0 + kk + kr) * Ndim + col0 + nc]);
        *reinterpret_cast<float4*>(&Bl[kk + kr][nc]) = v;
      }
    } else {
      int n = tid >> 3, kq = (tid & 7) * 4;
      #pragma unroll
      for (int nr = 0; nr < BNt; nr += 32) {
        float4 v = *reinterpret_cast<const float4*>(
            &Bb[(size_t)(col0 + n + nr) * Kdim + k0 + kq]);
        Bl[kq + 0][n + nr] = v.x; Bl[kq + 1][n + nr] = v.y;
        Bl[kq + 2][n + nr] = v.z; Bl[kq + 3][n + nr] = v.w;
      }
    }
    __syncthreads();

    #pragma unroll
    for (int kk = 0; kk < BKt; ++kk) {
      const float4 a4 = *reinterpret_cast<const float4*>(&Al[kk][rowr]);
      const float4 b4 = *reinterpret_cast<const float4*>(&Bl[kk][colr]);
      const float av[4] = {a4.x, a4.y, a4.z, a4.w};
      const float bw[4] = {b4.x, b4.y, b4.z, b4.w};
      #pragma unroll
      for (int i = 0; i < 4; ++i)
        #pragma unroll
        for (int j = 0; j < 4; ++j)
          acc[i][j] = fmaf(av[i], bw[j], acc[i][j]);
    }
    __syncthreads();
  }

  float* Cb = Cg + (size_t)b * Mdim * Ndim;
  #pragma unroll
  for (int i = 0; i < 4; ++i) {
    const int gi = row0 + rowr + i;
    float vals[4];
    #pragma unroll
    for (int j = 0; j < 4; ++j) {
      const int gj = col0 + colr + j;
      float s = acc[i][j];
      if (MODE == 1) { s += bias[gj]; s = fmaxf(s, 0.0f); }
      if (MODE == 2) {
        if (gi == gj) s -= 1e9f;
        float th = 1.0f - 2.0f / (__expf(2.0f * s) + 1.0f);   // tanh(s)
        float u  = noise[(size_t)b * Mdim * Ndim + (size_t)gi * Ndim + gj];
        float eps = -__logf(-__logf(u));                       // Gumbel
        s = (10.0f * th + 0.01f * eps) * (1.0f / 3.0f);
      }
      vals[j] = s;
    }
    *reinterpret_cast<float4*>(&Cb[(size_t)gi * Ndim + col0 + colr]) =
        make_float4(vals[0], vals[1], vals[2], vals[3]);
  }
}

// ----------------------------------------------------- row max + exp -------
__global__ __launch_bounds__(256) void rowexp_kernel(float* __restrict__ y)
{
  const int row = blockIdx.x;                 // 0 .. B*N
  float* p = y + (size_t)row * NN;
  const int t = threadIdx.x;
  float v0 = p[t], v1 = p[t + 256];
  float m = fmaxf(v0, v1);
  #pragma unroll
  for (int off = 32; off >= 1; off >>= 1) m = fmaxf(m, __shfl_xor(m, off));
  __shared__ float wm[4];
  if ((t & 63) == 0) wm[t >> 6] = m;
  __syncthreads();
  m = fmaxf(fmaxf(wm[0], wm[1]), fmaxf(wm[2], wm[3]));
  p[t]       = __expf(v0 - m);
  p[t + 256] = __expf(v1 - m);
}

// ----------------------------------------------------------- Sinkhorn ------
// Factorized: P_final = diag(r) P0 diag(c).
// 512 blocks = 32 per batch x 16 rows (2 blocks/CU for latency hiding).
// Column sums accumulate via agent-scope (IF$-resident) f32 atomicAdd into a
// per-batch double-buffered accumulator. Buffers are NEVER zeroed: on reuse
// each block adds (u_new - u_prev_contribution) — exact sum modulo ~30 ulp.
// Barrier: distributed per-block relaxed flags (256B padded); ordering by
// __syncthreads' vmcnt(0) drain (adds acked at coherence point before flag).
__global__ __launch_bounds__(256) void sinkhorn_kernel(
    const float* __restrict__ P0, float* __restrict__ cacc,
    unsigned int* __restrict__ flags, float* __restrict__ out)
{
  __shared__ float Pl[RB][513];
  __shared__ float cl[512];
  __shared__ float rl[RB];
  __shared__ float red[16][17];

  const int bid = blockIdx.x;
  const int b = bid >> 5, s = bid & 31;
  const int tid = threadIdx.x;
  const float* Pb = P0 + ((size_t)b * NN + s * RB) * NN;

  // stage 16x512 slab
  for (int f = tid; f < RB * 128; f += 256) {
    int r = f >> 7, c4 = (f & 127) * 4;
    float4 v = *reinterpret_cast<const float4*>(&Pb[(size_t)r * NN + c4]);
    Pl[r][c4 + 0] = v.x; Pl[r][c4 + 1] = v.y;
    Pl[r][c4 + 2] = v.z; Pl[r][c4 + 3] = v.w;
  }
  cl[tid] = 1.0f; cl[tid + 256] = 1.0f;
  __syncthreads();

  // r_i = 1 / sum_j Pl[i][j]*cl[j]; ch-staggered j to avoid bank conflicts
  auto row_update = [&]() {
    const int i = tid & 15, ch = tid >> 4;
    const int j0 = ch * 32, st = (ch * 8) & 31;
    float p = 0.0f;
    #pragma unroll
    for (int q = 0; q < 32; ++q) {
      const int j = j0 + ((q + st) & 31);
      p = fmaf(Pl[i][j], cl[j], p);
    }
    red[ch][i] = p;
    __syncthreads();
    if (tid < RB) {
      float v = 0.0f;
      #pragma unroll
      for (int q = 0; q < 16; ++q) v += red[q][tid];
      rl[tid] = 1.0f / v;
    }
    __syncthreads();
  };
  row_update();  // r0 = softmax row normalization (folded)

  unsigned int* myflag = flags + (size_t)(b * SB + s) * 64;
  float* ca0 = cacc + (size_t)b * 512;          // buffer 0 (even iters)
  float* ca1 = cacc + (size_t)(BB + b) * 512;   // buffer 1 (odd iters)
  float prevA0 = 0.f, prevA1 = 0.f, prevB0 = 0.f, prevB1 = 0.f;

  auto iter_body = [&](int it, float* ca, float& pv0, float& pv1) {
    // phase A: this slab's partial column sums of diag(r)P0 -> atomicAdd
    float u0 = 0.0f, u1 = 0.0f;
    #pragma unroll
    for (int i2 = 0; i2 < RB; ++i2) {
      const float rv = rl[i2];
      u0 = fmaf(Pl[i2][tid],       rv, u0);
      u1 = fmaf(Pl[i2][tid + 256], rv, u1);
    }
    __hip_atomic_fetch_add(&ca[tid],       u0 - pv0, __ATOMIC_RELAXED, SCOPE_AGENT);
    __hip_atomic_fetch_add(&ca[tid + 256], u1 - pv1, __ATOMIC_RELAXED, SCOPE_AGENT);
    pv0 = u0; pv1 = u1;
    __syncthreads();  // vmcnt(0): adds acked at coherence point

    if (tid == 0)
      __hip_atomic_store(myflag, (unsigned int)(it + 1),
                         __ATOMIC_RELAXED, SCOPE_AGENT);
    if (tid < SB) {
      const unsigned int* fp = flags + (size_t)(b * SB + tid) * 64;
      while (__hip_atomic_load(fp, __ATOMIC_RELAXED, SCOPE_AGENT) <
             (unsigned int)(it + 1))
        __builtin_amdgcn_s_sleep(1);
    }
    __syncthreads();

    // phase B: read summed colsums -> c; then local row matvec -> r
    float t0 = __hip_atomic_load(&ca[tid],       __ATOMIC_RELAXED, SCOPE_AGENT);
    float t1 = __hip_atomic_load(&ca[tid + 256], __ATOMIC_RELAXED, SCOPE_AGENT);
    cl[tid] = 1.0f / t0; cl[tid + 256] = 1.0f / t1;
    __syncthreads();
    row_update();
  };

  for (int i2 = 0; i2 < 30; ++i2) {
    iter_body(2 * i2,     ca0, prevA0, prevA1);
    iter_body(2 * i2 + 1, ca1, prevB0, prevB1);
  }

  // final: out = r_i * P0_ij * c_j   (reads LDS only)
  float* Ob = out + ((size_t)b * NN + s * RB) * NN;
  #pragma unroll
  for (int i = 0; i < RB; ++i) {
    const float rv = rl[i];
    Ob[(size_t)i * NN + tid]       = rv * Pl[i][tid]       * cl[tid];
    Ob[(size_t)i * NN + tid + 256] = rv * Pl[i][tid + 256] * cl[tid + 256];
  }
}

// ------------------------------------------------------------- launch ------
extern "C" void kernel_launch(void* const* d_in, const int* in_sizes, int n_in,
                              void* d_out, int out_size, void* d_ws, size_t ws_size,
                              hipStream_t stream)
{
  const float* points = (const float*)d_in[0];
  const float* dist   = (const float*)d_in[1];
  const float* noise  = (const float*)d_in[2];
  const float* Wemb   = (const float*)d_in[3];
  const float* bemb   = (const float*)d_in[4];
  const float* W1 = (const float*)d_in[5]; const float* b1 = (const float*)d_in[6];
  const float* W2 = (const float*)d_in[7]; const float* b2 = (const float*)d_in[8];
  const float* W3 = (const float*)d_in[9]; const float* b3 = (const float*)d_in[10];
  float* out = (float*)d_out;

  char* ws = (char*)d_ws;
  float* xa = (float*)ws;                                 // B*N*H f32 = 4 MB
  float* nb = (float*)(ws + (4u << 20));                  // B*N*H f32 = 4 MB
  float* cacc = (float*)(ws + (8u << 20));                // 2*16*512 f32 = 64 KB
  unsigned int* flags = (unsigned int*)(ws + (8u << 20) + (64u << 10)); // 128 KB

  // zero accumulators + flags (contiguous 192 KB)
  hipMemsetAsync(ws + (8u << 20), 0, (192u << 10), stream);

  // embed
  embed_kernel<<<(BB * NN * HH) / 256, 256, 0, stream>>>(points, Wemb, bemb, xa);

  // 3 GCN layers: nb = exp(-dist) @ x ; x = relu(nb @ W + b)
  constexpr int GRID_BMM = BB * (NN / BMt) * (HH / BNt);   // 256
  gemm_kernel<0, true,  false, NN, HH, NN><<<GRID_BMM, 256, 0, stream>>>(dist, xa, nullptr, nullptr, nb);
  gemm_kernel<1, false, false, NN, HH, HH><<<GRID_BMM, 256, 0, stream>>>(nb, W1, b1, nullptr, xa);
  gemm_kernel<0, true,  false, NN, HH, NN><<<GRID_BMM, 256, 0, stream>>>(dist, xa, nullptr, nullptr, nb);
  gemm_kernel<1, false, false, NN, HH, HH><<<GRID_BMM, 256, 0, stream>>>(nb, W2, b2, nullptr, xa);
  gemm_kernel<0, true,  false, NN, HH, NN><<<GRID_BMM, 256, 0, stream>>>(dist, xa, nullptr, nullptr, nb);
  gemm_kernel<1, false, false, NN, HH, HH><<<GRID_BMM, 256, 0, stream>>>(nb, W3, b3, nullptr, xa);

  // logits -> y (in d_out), fused mask/tanh/gumbel/T
  constexpr int GRID_LOG = BB * (NN / BMt) * (NN / BNt);   // 1024
  gemm_kernel<2, false, true, NN, NN, HH><<<GRID_LOG, 256, 0, stream>>>(xa, xa, nullptr, noise, out);

  // P0 = exp(y - rowmax)  (in place)
  rowexp_kernel<<<BB * NN, 256, 0, stream>>>(out);

  // Sinkhorn: cooperative launch only for co-residency; sync is hand-rolled.
  const float* P0c = out; float* caccP = cacc; unsigned int* flagsP = flags; float* outP = out;
  void* args[] = {(void*)&P0c, (void*)&caccP, (void*)&flagsP, (void*)&outP};
  hipLaunchCooperativeKernel(reinterpret_cast<void*>(sinkhorn_kernel),
                             dim3(BB * SB), dim3(256), args, 0, stream);
}

// Round 6
// 331.713 us; speedup vs baseline: 1.1314x; 1.1314x over previous
//
#include <hip/hip_runtime.h>

// Problem constants
#define BB 16
#define NN 512
#define HH 128
#define SB 32   // sinkhorn slabs (blocks) per batch
#define RB 16   // sinkhorn rows per slab

#define SCOPE_AGENT __HIP_MEMORY_SCOPE_AGENT

typedef _Float16 f16x8 __attribute__((ext_vector_type(8)));
typedef _Float16 f16x4 __attribute__((ext_vector_type(4)));
typedef float    f32x4 __attribute__((ext_vector_type(4)));

// ---------------------------------------------------------------- embed ----
// writes x0 (f16, [b][n][h]) and x0T (f16, [b][h][n])
__global__ __launch_bounds__(256) void embed16_kernel(
    const float* __restrict__ pts, const float* __restrict__ Wemb,
    const float* __restrict__ bemb, _Float16* __restrict__ xf,
    _Float16* __restrict__ xT)
{
  int idx = blockIdx.x * 256 + threadIdx.x;   // 0 .. B*N*16
  int ho = (idx & 15) * 8;                    // h-octet
  int bn = idx >> 4;
  int b = bn >> 9, n = bn & 511;
  float p0 = pts[bn * 2 + 0], p1 = pts[bn * 2 + 1];
  f16x8 h;
  #pragma unroll
  for (int i = 0; i < 8; ++i) {
    float v = fmaf(p0, Wemb[ho + i], fmaf(p1, Wemb[HH + ho + i], bemb[ho + i]));
    h[i] = (_Float16)v;
    xT[((size_t)b * HH + ho + i) * NN + n] = (_Float16)v;
  }
  *reinterpret_cast<f16x8*>(&xf[(size_t)bn * HH + ho]) = h;
}

// ------------------------------------------------------------ bmm (MFMA) ---
// nb[b][512][128] = exp(-dist[b]) @ x[b]   (B operand from xT rows, f16)
// grid = 16 batches x 16 row-tiles of 32; 256 thr = 4 waves (2x2).
__global__ __launch_bounds__(256) void bmm_mfma_kernel(
    const float* __restrict__ dist, const _Float16* __restrict__ xT,
    float* __restrict__ nb)
{
  __shared__ _Float16 Al[32][40];    // row stride 80B -> bank-spread
  __shared__ _Float16 Bl[128][40];
  const int bid = blockIdx.x;
  const int mt = bid & 15, b = bid >> 4;
  const int tid = threadIdx.x;
  const int row0 = mt * 32;
  const float* Ab = dist + ((size_t)b * NN + row0) * NN;
  const _Float16* xTb = xT + (size_t)b * HH * NN;

  const int wv = tid >> 6, lane = tid & 63;
  const int wm = wv >> 1, wn = wv & 1;
  const int fr = lane & 15, fo = lane >> 4;

  f32x4 acc[4] = {};

  for (int k0 = 0; k0 < NN; k0 += 32) {
    {  // stage A: 32 rows x 32 k, f32 -> exp(-x) -> f16
      const int r = tid >> 3, q = tid & 7;
      float4 v = *reinterpret_cast<const float4*>(&Ab[(size_t)r * NN + k0 + q * 4]);
      f16x4 h;
      h[0] = (_Float16)__expf(-v.x); h[1] = (_Float16)__expf(-v.y);
      h[2] = (_Float16)__expf(-v.z); h[3] = (_Float16)__expf(-v.w);
      *reinterpret_cast<f16x4*>(&Al[r][q * 4]) = h;
    }
    {  // stage B: 128 h-rows x 32 k from xT (contig k)
      #pragma unroll
      for (int it = 0; it < 2; ++it) {
        const int slot = it * 256 + tid;
        const int n = slot >> 2, q = slot & 3;
        f16x8 v = *reinterpret_cast<const f16x8*>(&xTb[(size_t)n * NN + k0 + q * 8]);
        *reinterpret_cast<f16x8*>(&Bl[n][q * 8]) = v;
      }
    }
    __syncthreads();
    f16x8 af = *reinterpret_cast<const f16x8*>(&Al[wm * 16 + fr][fo * 8]);
    #pragma unroll
    for (int nt = 0; nt < 4; ++nt) {
      f16x8 bf = *reinterpret_cast<const f16x8*>(&Bl[wn * 64 + nt * 16 + fr][fo * 8]);
      acc[nt] = __builtin_amdgcn_mfma_f32_16x16x32_f16(af, bf, acc[nt], 0, 0, 0);
    }
    __syncthreads();
  }
  float* Cb = nb + ((size_t)b * NN + row0) * HH;
  #pragma unroll
  for (int nt = 0; nt < 4; ++nt) {
    const int col = wn * 64 + nt * 16 + fr;
    #pragma unroll
    for (int m = 0; m < 4; ++m) {
      const int row = wm * 16 + fo * 4 + m;
      Cb[(size_t)row * HH + col] = acc[nt][m];
    }
  }
}

// --------------------------------------------------------- layer (f32) -----
// x = relu(nb @ W + b); M=512,N=128,K=128; writes x f16 rows + xT f16.
constexpr int BMt = 64, BNt = 64, BKt = 32;

__global__ __launch_bounds__(256) void layer_kernel(
    const float* __restrict__ Ag, const float* __restrict__ Bg,
    const float* __restrict__ bias,
    _Float16* __restrict__ xf, _Float16* __restrict__ xT)
{
  const int bid = blockIdx.x;
  const int tn  = bid % 2;
  const int tmi = (bid / 2) % 8;
  const int b   = bid / 16;
  const int tid = threadIdx.x;
  const int row0 = tmi * BMt, col0 = tn * BNt;

  __shared__ float Al[BKt][BMt + 4];
  __shared__ float Bl[BKt][BNt + 4];

  const float* Ab = Ag + (size_t)b * NN * HH;
  const float* Bb = Bg;   // shared weights

  const int rowr = (tid >> 4) * 4;
  const int colr = (tid & 15) * 4;

  float acc[4][4] = {};

  for (int k0 = 0; k0 < HH; k0 += BKt) {
    {
      int r = tid >> 3, kq = (tid & 7) * 4;
      #pragma unroll
      for (int rr = 0; rr < BMt; rr += 32) {
        float4 v = *reinterpret_cast<const float4*>(
            &Ab[(size_t)(row0 + r + rr) * HH + k0 + kq]);
        Al[kq + 0][r + rr] = v.x; Al[kq + 1][r + rr] = v.y;
        Al[kq + 2][r + rr] = v.z; Al[kq + 3][r + rr] = v.w;
      }
    }
    {
      int kk = tid >> 4, nc = (tid & 15) * 4;
      #pragma unroll
      for (int kr = 0; kr < BKt; kr += 16) {
        float4 v = *reinterpret_cast<const float4*>(
            &Bb[(size_t)(k0 + kk + kr) * HH + col0 + nc]);
        *reinterpret_cast<float4*>(&Bl[kk + kr][nc]) = v;
      }
    }
    __syncthreads();
    #pragma unroll
    for (int kk = 0; kk < BKt; ++kk) {
      const float4 a4 = *reinterpret_cast<const float4*>(&Al[kk][rowr]);
      const float4 b4 = *reinterpret_cast<const float4*>(&Bl[kk][colr]);
      const float av[4] = {a4.x, a4.y, a4.z, a4.w};
      const float bw[4] = {b4.x, b4.y, b4.z, b4.w};
      #pragma unroll
      for (int i = 0; i < 4; ++i)
        #pragma unroll
        for (int j = 0; j < 4; ++j)
          acc[i][j] = fmaf(av[i], bw[j], acc[i][j]);
    }
    __syncthreads();
  }

  float vals[4][4];
  #pragma unroll
  for (int i = 0; i < 4; ++i)
    #pragma unroll
    for (int j = 0; j < 4; ++j)
      vals[i][j] = fmaxf(acc[i][j] + bias[col0 + colr + j], 0.0f);

  _Float16* xfb = xf + (size_t)b * NN * HH;
  _Float16* xTb = xT + (size_t)b * HH * NN;
  #pragma unroll
  for (int i = 0; i < 4; ++i) {
    f16x4 hr;
    #pragma unroll
    for (int j = 0; j < 4; ++j) hr[j] = (_Float16)vals[i][j];
    *reinterpret_cast<f16x4*>(&xfb[(size_t)(row0 + rowr + i) * HH + col0 + colr]) = hr;
  }
  #pragma unroll
  for (int j = 0; j < 4; ++j) {
    f16x4 hc;
    #pragma unroll
    for (int i = 0; i < 4; ++i) hc[i] = (_Float16)vals[i][j];
    *reinterpret_cast<f16x4*>(&xTb[(size_t)(col0 + colr + j) * NN + row0 + rowr]) = hc;
  }
}

// --------------------------------------------------------- logits (MFMA) ---
// y[b][i][j] = (10*tanh(x_i . x_j - 1e9*[i==j]) + 0.01*gumbel)/3
// Both operands from xf rows. grid = 16 x 8 x 8; BM=BN=64, K=128.
__global__ __launch_bounds__(256) void logits_mfma_kernel(
    const _Float16* __restrict__ xf, const float* __restrict__ noise,
    float* __restrict__ y)
{
  __shared__ _Float16 Al[64][136];
  __shared__ _Float16 Bl[64][136];
  const int bid = blockIdx.x;
  const int tn = bid & 7, tm = (bid >> 3) & 7, b = bid >> 6;
  const int row0 = tm * 64, col0 = tn * 64;
  const _Float16* xb = xf + (size_t)b * NN * HH;
  const int tid = threadIdx.x;

  #pragma unroll
  for (int it = 0; it < 4; ++it) {
    const int slot = it * 256 + tid;
    const int r = slot >> 4, q = slot & 15;
    *reinterpret_cast<f16x8*>(&Al[r][q * 8]) =
        *reinterpret_cast<const f16x8*>(&xb[(size_t)(row0 + r) * HH + q * 8]);
    *reinterpret_cast<f16x8*>(&Bl[r][q * 8]) =
        *reinterpret_cast<const f16x8*>(&xb[(size_t)(col0 + r) * HH + q * 8]);
  }
  __syncthreads();

  const int wv = tid >> 6, lane = tid & 63;
  const int wm = wv >> 1, wn = wv & 1;
  const int fr = lane & 15, fo = lane >> 4;
  f32x4 acc[2][2] = {};
  #pragma unroll
  for (int ks = 0; ks < 4; ++ks) {
    f16x8 af[2], bf[2];
    #pragma unroll
    for (int t2 = 0; t2 < 2; ++t2) {
      af[t2] = *reinterpret_cast<const f16x8*>(&Al[wm * 32 + t2 * 16 + fr][ks * 32 + fo * 8]);
      bf[t2] = *reinterpret_cast<const f16x8*>(&Bl[wn * 32 + t2 * 16 + fr][ks * 32 + fo * 8]);
    }
    #pragma unroll
    for (int i = 0; i < 2; ++i)
      #pragma unroll
      for (int j = 0; j < 2; ++j)
        acc[i][j] = __builtin_amdgcn_mfma_f32_16x16x32_f16(af[i], bf[j], acc[i][j], 0, 0, 0);
  }

  float* yb = y + (size_t)b * NN * NN;
  const float* nzb = noise + (size_t)b * NN * NN;
  #pragma unroll
  for (int i = 0; i < 2; ++i) {
    #pragma unroll
    for (int j = 0; j < 2; ++j) {
      const int gj = col0 + wn * 32 + j * 16 + fr;
      #pragma unroll
      for (int m = 0; m < 4; ++m) {
        const int gi = row0 + wm * 32 + i * 16 + fo * 4 + m;
        float s = acc[i][j][m];
        if (gi == gj) s -= 1e9f;
        float th = 1.0f - 2.0f / (__expf(2.0f * s) + 1.0f);    // tanh(s)
        float u  = nzb[(size_t)gi * NN + gj];
        float eps = -__logf(-__logf(u));                        // Gumbel
        yb[(size_t)gi * NN + gj] = (10.0f * th + 0.01f * eps) * (1.0f / 3.0f);
      }
    }
  }
}

// ----------------------------------------------------- row max + exp -------
__global__ __launch_bounds__(256) void rowexp_kernel(float* __restrict__ y)
{
  const int row = blockIdx.x;                 // 0 .. B*N
  float* p = y + (size_t)row * NN;
  const int t = threadIdx.x;
  float v0 = p[t], v1 = p[t + 256];
  float m = fmaxf(v0, v1);
  #pragma unroll
  for (int off = 32; off >= 1; off >>= 1) m = fmaxf(m, __shfl_xor(m, off));
  __shared__ float wm[4];
  if ((t & 63) == 0) wm[t >> 6] = m;
  __syncthreads();
  m = fmaxf(fmaxf(wm[0], wm[1]), fmaxf(wm[2], wm[3]));
  p[t]       = __expf(v0 - m);
  p[t + 256] = __expf(v1 - m);
}

// ----------------------------------------------------------- Sinkhorn ------
// R4-proven version, verbatim. Factorized P_final = diag(r) P0 diag(c).
// 512 blocks = 32/batch x 16 rows. Agent-scope atomicAdd colsum accumulation
// (delta trick, never zeroed), distributed relaxed flags, vmcnt(0)-ordered.
__global__ __launch_bounds__(256) void sinkhorn_kernel(
    const float* __restrict__ P0, float* __restrict__ cacc,
    unsigned int* __restrict__ flags, float* __restrict__ out)
{
  __shared__ float Pl[RB][513];
  __shared__ float cl[512];
  __shared__ float rl[RB];
  __shared__ float red[16][17];

  const int bid = blockIdx.x;
  const int b = bid >> 5, s = bid & 31;
  const int tid = threadIdx.x;
  const float* Pb = P0 + ((size_t)b * NN + s * RB) * NN;

  for (int f = tid; f < RB * 128; f += 256) {
    int r = f >> 7, c4 = (f & 127) * 4;
    float4 v = *reinterpret_cast<const float4*>(&Pb[(size_t)r * NN + c4]);
    Pl[r][c4 + 0] = v.x; Pl[r][c4 + 1] = v.y;
    Pl[r][c4 + 2] = v.z; Pl[r][c4 + 3] = v.w;
  }
  cl[tid] = 1.0f; cl[tid + 256] = 1.0f;
  __syncthreads();

  auto row_update = [&]() {
    const int i = tid & 15, ch = tid >> 4;
    const int j0 = ch * 32, st = (ch * 8) & 31;
    float p = 0.0f;
    #pragma unroll
    for (int q = 0; q < 32; ++q) {
      const int j = j0 + ((q + st) & 31);
      p = fmaf(Pl[i][j], cl[j], p);
    }
    red[ch][i] = p;
    __syncthreads();
    if (tid < RB) {
      float v = 0.0f;
      #pragma unroll
      for (int q = 0; q < 16; ++q) v += red[q][tid];
      rl[tid] = 1.0f / v;
    }
    __syncthreads();
  };
  row_update();  // r0 = softmax row normalization (folded)

  unsigned int* myflag = flags + (size_t)(b * SB + s) * 64;
  float* ca0 = cacc + (size_t)b * 512;
  float* ca1 = cacc + (size_t)(BB + b) * 512;
  float prevA0 = 0.f, prevA1 = 0.f, prevB0 = 0.f, prevB1 = 0.f;

  auto iter_body = [&](int it, float* ca, float& pv0, float& pv1) {
    float u0 = 0.0f, u1 = 0.0f;
    #pragma unroll
    for (int i2 = 0; i2 < RB; ++i2) {
      const float rv = rl[i2];
      u0 = fmaf(Pl[i2][tid],       rv, u0);
      u1 = fmaf(Pl[i2][tid + 256], rv, u1);
    }
    __hip_atomic_fetch_add(&ca[tid],       u0 - pv0, __ATOMIC_RELAXED, SCOPE_AGENT);
    __hip_atomic_fetch_add(&ca[tid + 256], u1 - pv1, __ATOMIC_RELAXED, SCOPE_AGENT);
    pv0 = u0; pv1 = u1;
    __syncthreads();  // vmcnt(0): adds acked at coherence point

    if (tid == 0)
      __hip_atomic_store(myflag, (unsigned int)(it + 1),
                         __ATOMIC_RELAXED, SCOPE_AGENT);
    if (tid < SB) {
      const unsigned int* fp = flags + (size_t)(b * SB + tid) * 64;
      while (__hip_atomic_load(fp, __ATOMIC_RELAXED, SCOPE_AGENT) <
             (unsigned int)(it + 1))
        __builtin_amdgcn_s_sleep(1);
    }
    __syncthreads();

    float t0 = __hip_atomic_load(&ca[tid],       __ATOMIC_RELAXED, SCOPE_AGENT);
    float t1 = __hip_atomic_load(&ca[tid + 256], __ATOMIC_RELAXED, SCOPE_AGENT);
    cl[tid] = 1.0f / t0; cl[tid + 256] = 1.0f / t1;
    __syncthreads();
    row_update();
  };

  for (int i2 = 0; i2 < 30; ++i2) {
    iter_body(2 * i2,     ca0, prevA0, prevA1);
    iter_body(2 * i2 + 1, ca1, prevB0, prevB1);
  }

  float* Ob = out + ((size_t)b * NN + s * RB) * NN;
  #pragma unroll
  for (int i = 0; i < RB; ++i) {
    const float rv = rl[i];
    Ob[(size_t)i * NN + tid]       = rv * Pl[i][tid]       * cl[tid];
    Ob[(size_t)i * NN + tid + 256] = rv * Pl[i][tid + 256] * cl[tid + 256];
  }
}

// ------------------------------------------------------------- launch ------
extern "C" void kernel_launch(void* const* d_in, const int* in_sizes, int n_in,
                              void* d_out, int out_size, void* d_ws, size_t ws_size,
                              hipStream_t stream)
{
  const float* points = (const float*)d_in[0];
  const float* dist   = (const float*)d_in[1];
  const float* noise  = (const float*)d_in[2];
  const float* Wemb   = (const float*)d_in[3];
  const float* bemb   = (const float*)d_in[4];
  const float* W1 = (const float*)d_in[5]; const float* b1 = (const float*)d_in[6];
  const float* W2 = (const float*)d_in[7]; const float* b2 = (const float*)d_in[8];
  const float* W3 = (const float*)d_in[9]; const float* b3 = (const float*)d_in[10];
  float* out = (float*)d_out;

  char* ws = (char*)d_ws;
  float*     nb = (float*)ws;                         // 4 MB
  _Float16*  xf = (_Float16*)(ws + (4u << 20));       // 2 MB
  _Float16*  xT = (_Float16*)(ws + (6u << 20));       // 2 MB
  char* ctrl = ws + (8u << 20);
  float*        cacc  = (float*)ctrl;                 // 64 KB
  unsigned int* flags = (unsigned int*)(ctrl + (64u << 10));  // 128 KB

  hipMemsetAsync(ctrl, 0, (192u << 10), stream);

  // embed -> x0 f16 + x0T f16
  embed16_kernel<<<512, 256, 0, stream>>>(points, Wemb, bemb, xf, xT);

  // 3 GCN layers: nb = exp(-dist) @ x (MFMA f16); x = relu(nb@W+b) (f32)
  bmm_mfma_kernel<<<256, 256, 0, stream>>>(dist, xT, nb);
  layer_kernel<<<256, 256, 0, stream>>>(nb, W1, b1, xf, xT);
  bmm_mfma_kernel<<<256, 256, 0, stream>>>(dist, xT, nb);
  layer_kernel<<<256, 256, 0, stream>>>(nb, W2, b2, xf, xT);
  bmm_mfma_kernel<<<256, 256, 0, stream>>>(dist, xT, nb);
  layer_kernel<<<256, 256, 0, stream>>>(nb, W3, b3, xf, xT);

  // logits (MFMA f16) + fused mask/tanh/gumbel/T -> y in d_out
  logits_mfma_kernel<<<1024, 256, 0, stream>>>(xf, noise, out);

  // P0 = exp(y - rowmax)  (in place)
  rowexp_kernel<<<BB * NN, 256, 0, stream>>>(out);

  // Sinkhorn (R4-proven protocol)
  const float* P0c = out; float* caccP = cacc; unsigned int* flagsP = flags; float* outP = out;
  void* args[] = {(void*)&P0c, (void*)&caccP, (void*)&flagsP, (void*)&outP};
  hipLaunchCooperativeKernel(reinterpret_cast<void*>(sinkhorn_kernel),
                             dim3(BB * SB), dim3(256), args, 0, stream);
}

// Round 8
// 149.018 us; speedup vs baseline: 2.5184x; 2.2260x over previous
//
#include <hip/hip_runtime.h>

// Problem constants
#define BB 16
#define NN 512
#define HH 128
#define SB 32   // sinkhorn slabs (blocks) per batch
#define RB 16   // sinkhorn rows per slab

#define SCOPE_AGENT __HIP_MEMORY_SCOPE_AGENT

typedef _Float16 f16x8 __attribute__((ext_vector_type(8)));
typedef _Float16 f16x4 __attribute__((ext_vector_type(4)));
typedef float    f32x4 __attribute__((ext_vector_type(4)));

// ---------------------------------------------------------------- embed ----
// writes x0 (f16, [b][n][h]) and x0T (f16, [b][h][n])
__global__ __launch_bounds__(256) void embed16_kernel(
    const float* __restrict__ pts, const float* __restrict__ Wemb,
    const float* __restrict__ bemb, _Float16* __restrict__ xf,
    _Float16* __restrict__ xT)
{
  int idx = blockIdx.x * 256 + threadIdx.x;   // 0 .. B*N*16
  int ho = (idx & 15) * 8;                    // h-octet
  int bn = idx >> 4;
  int b = bn >> 9, n = bn & 511;
  float p0 = pts[bn * 2 + 0], p1 = pts[bn * 2 + 1];
  f16x8 h;
  #pragma unroll
  for (int i = 0; i < 8; ++i) {
    float v = fmaf(p0, Wemb[ho + i], fmaf(p1, Wemb[HH + ho + i], bemb[ho + i]));
    h[i] = (_Float16)v;
    xT[((size_t)b * HH + ho + i) * NN + n] = (_Float16)v;
  }
  *reinterpret_cast<f16x8*>(&xf[(size_t)bn * HH + ho]) = h;
}

// ------------------------------------------------------------ bmm (MFMA) ---
// nb[b][512][128] = exp(-dist[b]) @ x[b]   (B operand from xT rows, f16)
// grid = 16 batches x 16 row-tiles of 32; 256 thr = 4 waves (2x2).
__global__ __launch_bounds__(256) void bmm_mfma_kernel(
    const float* __restrict__ dist, const _Float16* __restrict__ xT,
    float* __restrict__ nb)
{
  __shared__ _Float16 Al[32][40];    // row stride 80B -> bank-spread
  __shared__ _Float16 Bl[128][40];
  const int bid = blockIdx.x;
  const int mt = bid & 15, b = bid >> 4;
  const int tid = threadIdx.x;
  const int row0 = mt * 32;
  const float* Ab = dist + ((size_t)b * NN + row0) * NN;
  const _Float16* xTb = xT + (size_t)b * HH * NN;

  const int wv = tid >> 6, lane = tid & 63;
  const int wm = wv >> 1, wn = wv & 1;
  const int fr = lane & 15, fo = lane >> 4;

  f32x4 acc[4] = {};

  for (int k0 = 0; k0 < NN; k0 += 32) {
    {  // stage A: 32 rows x 32 k, f32 -> exp(-x) -> f16
      const int r = tid >> 3, q = tid & 7;
      float4 v = *reinterpret_cast<const float4*>(&Ab[(size_t)r * NN + k0 + q * 4]);
      f16x4 h;
      h[0] = (_Float16)__expf(-v.x); h[1] = (_Float16)__expf(-v.y);
      h[2] = (_Float16)__expf(-v.z); h[3] = (_Float16)__expf(-v.w);
      *reinterpret_cast<f16x4*>(&Al[r][q * 4]) = h;
    }
    {  // stage B: 128 h-rows x 32 k from xT (contig k)
      #pragma unroll
      for (int it = 0; it < 2; ++it) {
        const int slot = it * 256 + tid;
        const int n = slot >> 2, q = slot & 3;
        f16x8 v = *reinterpret_cast<const f16x8*>(&xTb[(size_t)n * NN + k0 + q * 8]);
        *reinterpret_cast<f16x8*>(&Bl[n][q * 8]) = v;
      }
    }
    __syncthreads();
    f16x8 af = *reinterpret_cast<const f16x8*>(&Al[wm * 16 + fr][fo * 8]);
    #pragma unroll
    for (int nt = 0; nt < 4; ++nt) {
      f16x8 bf = *reinterpret_cast<const f16x8*>(&Bl[wn * 64 + nt * 16 + fr][fo * 8]);
      acc[nt] = __builtin_amdgcn_mfma_f32_16x16x32_f16(af, bf, acc[nt], 0, 0, 0);
    }
    __syncthreads();
  }
  float* Cb = nb + ((size_t)b * NN + row0) * HH;
  #pragma unroll
  for (int nt = 0; nt < 4; ++nt) {
    const int col = wn * 64 + nt * 16 + fr;
    #pragma unroll
    for (int m = 0; m < 4; ++m) {
      const int row = wm * 16 + fo * 4 + m;
      Cb[(size_t)row * HH + col] = acc[nt][m];
    }
  }
}

// --------------------------------------------------------- layer (f32) -----
// x = relu(nb @ W + b); M=512,N=128,K=128; writes x f16 rows + xT f16.
constexpr int BMt = 64, BNt = 64, BKt = 32;

__global__ __launch_bounds__(256) void layer_kernel(
    const float* __restrict__ Ag, const float* __restrict__ Bg,
    const float* __restrict__ bias,
    _Float16* __restrict__ xf, _Float16* __restrict__ xT)
{
  const int bid = blockIdx.x;
  const int tn  = bid % 2;
  const int tmi = (bid / 2) % 8;
  const int b   = bid / 16;
  const int tid = threadIdx.x;
  const int row0 = tmi * BMt, col0 = tn * BNt;

  __shared__ float Al[BKt][BMt + 4];
  __shared__ float Bl[BKt][BNt + 4];

  const float* Ab = Ag + (size_t)b * NN * HH;
  const float* Bb = Bg;   // shared weights

  const int rowr = (tid >> 4) * 4;
  const int colr = (tid & 15) * 4;

  float acc[4][4] = {};

  for (int k0 = 0; k0 < HH; k0 += BKt) {
    {
      int r = tid >> 3, kq = (tid & 7) * 4;
      #pragma unroll
      for (int rr = 0; rr < BMt; rr += 32) {
        float4 v = *reinterpret_cast<const float4*>(
            &Ab[(size_t)(row0 + r + rr) * HH + k0 + kq]);
        Al[kq + 0][r + rr] = v.x; Al[kq + 1][r + rr] = v.y;
        Al[kq + 2][r + rr] = v.z; Al[kq + 3][r + rr] = v.w;
      }
    }
    {
      int kk = tid >> 4, nc = (tid & 15) * 4;
      #pragma unroll
      for (int kr = 0; kr < BKt; kr += 16) {
        float4 v = *reinterpret_cast<const float4*>(
            &Bb[(size_t)(k0 + kk + kr) * HH + col0 + nc]);
        *reinterpret_cast<float4*>(&Bl[kk + kr][nc]) = v;
      }
    }
    __syncthreads();
    #pragma unroll
    for (int kk = 0; kk < BKt; ++kk) {
      const float4 a4 = *reinterpret_cast<const float4*>(&Al[kk][rowr]);
      const float4 b4 = *reinterpret_cast<const float4*>(&Bl[kk][colr]);
      const float av[4] = {a4.x, a4.y, a4.z, a4.w};
      const float bw[4] = {b4.x, b4.y, b4.z, b4.w};
      #pragma unroll
      for (int i = 0; i < 4; ++i)
        #pragma unroll
        for (int j = 0; j < 4; ++j)
          acc[i][j] = fmaf(av[i], bw[j], acc[i][j]);
    }
    __syncthreads();
  }

  float vals[4][4];
  #pragma unroll
  for (int i = 0; i < 4; ++i)
    #pragma unroll
    for (int j = 0; j < 4; ++j)
      vals[i][j] = fmaxf(acc[i][j] + bias[col0 + colr + j], 0.0f);

  _Float16* xfb = xf + (size_t)b * NN * HH;
  _Float16* xTb = xT + (size_t)b * HH * NN;
  #pragma unroll
  for (int i = 0; i < 4; ++i) {
    f16x4 hr;
    #pragma unroll
    for (int j = 0; j < 4; ++j) hr[j] = (_Float16)vals[i][j];
    *reinterpret_cast<f16x4*>(&xfb[(size_t)(row0 + rowr + i) * HH + col0 + colr]) = hr;
  }
  #pragma unroll
  for (int j = 0; j < 4; ++j) {
    f16x4 hc;
    #pragma unroll
    for (int i = 0; i < 4; ++i) hc[i] = (_Float16)vals[i][j];
    *reinterpret_cast<f16x4*>(&xTb[(size_t)(col0 + colr + j) * NN + row0 + rowr]) = hc;
  }
}

// --------------------------------------------------------- logits (MFMA) ---
// y[b][i][j] = (10*tanh(x_i . x_j - 1e9*[i==j]) + 0.01*gumbel)/3
__global__ __launch_bounds__(256) void logits_mfma_kernel(
    const _Float16* __restrict__ xf, const float* __restrict__ noise,
    float* __restrict__ y)
{
  __shared__ _Float16 Al[64][136];
  __shared__ _Float16 Bl[64][136];
  const int bid = blockIdx.x;
  const int tn = bid & 7, tm = (bid >> 3) & 7, b = bid >> 6;
  const int row0 = tm * 64, col0 = tn * 64;
  const _Float16* xb = xf + (size_t)b * NN * HH;
  const int tid = threadIdx.x;

  #pragma unroll
  for (int it = 0; it < 4; ++it) {
    const int slot = it * 256 + tid;
    const int r = slot >> 4, q = slot & 15;
    *reinterpret_cast<f16x8*>(&Al[r][q * 8]) =
        *reinterpret_cast<const f16x8*>(&xb[(size_t)(row0 + r) * HH + q * 8]);
    *reinterpret_cast<f16x8*>(&Bl[r][q * 8]) =
        *reinterpret_cast<const f16x8*>(&xb[(size_t)(col0 + r) * HH + q * 8]);
  }
  __syncthreads();

  const int wv = tid >> 6, lane = tid & 63;
  const int wm = wv >> 1, wn = wv & 1;
  const int fr = lane & 15, fo = lane >> 4;
  f32x4 acc[2][2] = {};
  #pragma unroll
  for (int ks = 0; ks < 4; ++ks) {
    f16x8 af[2], bf[2];
    #pragma unroll
    for (int t2 = 0; t2 < 2; ++t2) {
      af[t2] = *reinterpret_cast<const f16x8*>(&Al[wm * 32 + t2 * 16 + fr][ks * 32 + fo * 8]);
      bf[t2] = *reinterpret_cast<const f16x8*>(&Bl[wn * 32 + t2 * 16 + fr][ks * 32 + fo * 8]);
    }
    #pragma unroll
    for (int i = 0; i < 2; ++i)
      #pragma unroll
      for (int j = 0; j < 2; ++j)
        acc[i][j] = __builtin_amdgcn_mfma_f32_16x16x32_f16(af[i], bf[j], acc[i][j], 0, 0, 0);
  }

  float* yb = y + (size_t)b * NN * NN;
  const float* nzb = noise + (size_t)b * NN * NN;
  #pragma unroll
  for (int i = 0; i < 2; ++i) {
    #pragma unroll
    for (int j = 0; j < 2; ++j) {
      const int gj = col0 + wn * 32 + j * 16 + fr;
      #pragma unroll
      for (int m = 0; m < 4; ++m) {
        const int gi = row0 + wm * 32 + i * 16 + fo * 4 + m;
        float s = acc[i][j][m];
        if (gi == gj) s -= 1e9f;
        float th = 1.0f - 2.0f / (__expf(2.0f * s) + 1.0f);    // tanh(s)
        float u  = nzb[(size_t)gi * NN + gj];
        float eps = -__logf(-__logf(u));                        // Gumbel
        yb[(size_t)gi * NN + gj] = (10.0f * th + 0.01f * eps) * (1.0f / 3.0f);
      }
    }
  }
}

// ----------------------------------------------------- row max + exp -------
__global__ __launch_bounds__(256) void rowexp_kernel(float* __restrict__ y)
{
  const int row = blockIdx.x;                 // 0 .. B*N
  float* p = y + (size_t)row * NN;
  const int t = threadIdx.x;
  float v0 = p[t], v1 = p[t + 256];
  float m = fmaxf(v0, v1);
  #pragma unroll
  for (int off = 32; off >= 1; off >>= 1) m = fmaxf(m, __shfl_xor(m, off));
  __shared__ float wm[4];
  if ((t & 63) == 0) wm[t >> 6] = m;
  __syncthreads();
  m = fmaxf(fmaxf(wm[0], wm[1]), fmaxf(wm[2], wm[3]));
  p[t]       = __expf(v0 - m);
  p[t + 256] = __expf(v1 - m);
}

// ----------------------------------------------------------- Sinkhorn ------
// R6-proven protocol (32 distributed flags, agent-scope relaxed atomics,
// delta-trick accumulators) + deadlock-free early exit:
//   flag value = ((it+1)<<1) | convbit   (still strictly monotonic).
// Every block's poll already reads all 32 flags; the AND of the published
// convbits is computed from the SAME 32 words by every block -> unanimous
// stop decision by construction (no reliance on identical local dm).
// convbit(it) = [dm(it-1) < 1e-5], dm = max_j|colsum_j*c_old_j - 1|.
// Stopping error vs 60-iter reference ~1e-7 << 4.1e-5 threshold.
__global__ __launch_bounds__(256) void sinkhorn_kernel(
    const float* __restrict__ P0, float* __restrict__ cacc,
    unsigned int* __restrict__ flags, float* __restrict__ out)
{
  __shared__ float Pl[RB][513];
  __shared__ float cl[512];
  __shared__ float rl[RB];
  __shared__ float red[16][17];
  __shared__ float wmax[4];
  __shared__ int stopf;

  const int bid = blockIdx.x;
  const int b = bid >> 5, s = bid & 31;
  const int tid = threadIdx.x;
  const float* Pb = P0 + ((size_t)b * NN + s * RB) * NN;

  for (int f = tid; f < RB * 128; f += 256) {
    int r = f >> 7, c4 = (f & 127) * 4;
    float4 v = *reinterpret_cast<const float4*>(&Pb[(size_t)r * NN + c4]);
    Pl[r][c4 + 0] = v.x; Pl[r][c4 + 1] = v.y;
    Pl[r][c4 + 2] = v.z; Pl[r][c4 + 3] = v.w;
  }
  cl[tid] = 1.0f; cl[tid + 256] = 1.0f;
  __syncthreads();

  auto row_update = [&]() {
    const int i = tid & 15, ch = tid >> 4;
    const int j0 = ch * 32, st = (ch * 8) & 31;
    float p = 0.0f;
    #pragma unroll
    for (int q = 0; q < 32; ++q) {
      const int j = j0 + ((q + st) & 31);
      p = fmaf(Pl[i][j], cl[j], p);
    }
    red[ch][i] = p;
    __syncthreads();
    if (tid < RB) {
      float v = 0.0f;
      #pragma unroll
      for (int q = 0; q < 16; ++q) v += red[q][tid];
      rl[tid] = 1.0f / v;
    }
    __syncthreads();
  };
  row_update();  // r0 = softmax row normalization (folded)

  unsigned int* myflag = flags + (size_t)(b * SB + s) * 64;
  float* ca0 = cacc + (size_t)b * 512;
  float* ca1 = cacc + (size_t)(BB + b) * 512;
  float pA0 = 0.f, pA1 = 0.f, pB0 = 0.f, pB1 = 0.f;
  unsigned int convbit = 0;

  for (int it = 0; it < 60; ++it) {
    float* ca  = (it & 1) ? ca1 : ca0;
    float& pv0 = (it & 1) ? pB0 : pA0;
    float& pv1 = (it & 1) ? pB1 : pA1;

    // phase A: partial column sums of diag(r)P0 over this slab -> atomicAdd
    float u0 = 0.0f, u1 = 0.0f;
    #pragma unroll
    for (int i2 = 0; i2 < RB; ++i2) {
      const float rv = rl[i2];
      u0 = fmaf(Pl[i2][tid],       rv, u0);
      u1 = fmaf(Pl[i2][tid + 256], rv, u1);
    }
    __hip_atomic_fetch_add(&ca[tid],       u0 - pv0, __ATOMIC_RELAXED, SCOPE_AGENT);
    __hip_atomic_fetch_add(&ca[tid + 256], u1 - pv1, __ATOMIC_RELAXED, SCOPE_AGENT);
    pv0 = u0; pv1 = u1;
    __syncthreads();  // vmcnt(0): this block's adds acked at coherence point

    // arrive: monotonic flag carries the convergence vote in bit 0
    if (tid == 0)
      __hip_atomic_store(myflag, ((unsigned int)(it + 1) << 1) | convbit,
                         __ATOMIC_RELAXED, SCOPE_AGENT);
    // wait (wave 0): 32 lanes poll the 32 flags; AND the votes via ballot
    if (tid < 64) {
      unsigned int v = 3u;              // lanes 32..63: arrived + vote yes
      if (tid < SB) {
        const unsigned int* fp = flags + (size_t)(b * SB + tid) * 64;
        do {
          v = __hip_atomic_load(fp, __ATOMIC_RELAXED, SCOPE_AGENT);
          if ((v >> 1) >= (unsigned int)(it + 1)) break;
          __builtin_amdgcn_s_sleep(1);
        } while (true);
      }
      unsigned long long m = __ballot((v & 1u) != 0u);
      if (tid == 0) stopf = ((m & 0xFFFFFFFFull) == 0xFFFFFFFFull) ? 1 : 0;
    }
    __syncthreads();
    if (stopf) break;   // unanimous: derived from the same 32 published words

    // phase B: read summed colsums; measure dm; update c; row pass
    float t0 = __hip_atomic_load(&ca[tid],       __ATOMIC_RELAXED, SCOPE_AGENT);
    float t1 = __hip_atomic_load(&ca[tid + 256], __ATOMIC_RELAXED, SCOPE_AGENT);
    float d = fmaxf(fabsf(fmaf(t0, cl[tid], -1.0f)),
                    fabsf(fmaf(t1, cl[tid + 256], -1.0f)));
    #pragma unroll
    for (int off = 32; off >= 1; off >>= 1) d = fmaxf(d, __shfl_xor(d, off));
    if ((tid & 63) == 0) wmax[tid >> 6] = d;
    cl[tid] = 1.0f / t0; cl[tid + 256] = 1.0f / t1;
    __syncthreads();
    const float dm = fmaxf(fmaxf(wmax[0], wmax[1]), fmaxf(wmax[2], wmax[3]));
    convbit = (dm < 1e-5f) ? 1u : 0u;
    row_update();
  }

  // final: out = r_i * P0_ij * c_j   (reads LDS only)
  float* Ob = out + ((size_t)b * NN + s * RB) * NN;
  #pragma unroll
  for (int i = 0; i < RB; ++i) {
    const float rv = rl[i];
    Ob[(size_t)i * NN + tid]       = rv * Pl[i][tid]       * cl[tid];
    Ob[(size_t)i * NN + tid + 256] = rv * Pl[i][tid + 256] * cl[tid + 256];
  }
}

// ------------------------------------------------------------- launch ------
extern "C" void kernel_launch(void* const* d_in, const int* in_sizes, int n_in,
                              void* d_out, int out_size, void* d_ws, size_t ws_size,
                              hipStream_t stream)
{
  const float* points = (const float*)d_in[0];
  const float* dist   = (const float*)d_in[1];
  const float* noise  = (const float*)d_in[2];
  const float* Wemb   = (const float*)d_in[3];
  const float* bemb   = (const float*)d_in[4];
  const float* W1 = (const float*)d_in[5]; const float* b1 = (const float*)d_in[6];
  const float* W2 = (const float*)d_in[7]; const float* b2 = (const float*)d_in[8];
  const float* W3 = (const float*)d_in[9]; const float* b3 = (const float*)d_in[10];
  float* out = (float*)d_out;

  char* ws = (char*)d_ws;                             // proven budget: 8.2 MB
  float*     nb = (float*)ws;                         // 4 MB
  _Float16*  xf = (_Float16*)(ws + (4u << 20));       // 2 MB
  _Float16*  xT = (_Float16*)(ws + (6u << 20));       // 2 MB
  char* ctrl = ws + (8u << 20);
  float*        cacc  = (float*)ctrl;                 // 64 KB
  unsigned int* flags = (unsigned int*)(ctrl + (64u << 10));  // 128 KB

  hipMemsetAsync(ctrl, 0, (192u << 10), stream);

  // embed -> x0 f16 + x0T f16
  embed16_kernel<<<512, 256, 0, stream>>>(points, Wemb, bemb, xf, xT);

  // 3 GCN layers: nb = exp(-dist) @ x (MFMA f16); x = relu(nb@W+b) (f32)
  bmm_mfma_kernel<<<256, 256, 0, stream>>>(dist, xT, nb);
  layer_kernel<<<256, 256, 0, stream>>>(nb, W1, b1, xf, xT);
  bmm_mfma_kernel<<<256, 256, 0, stream>>>(dist, xT, nb);
  layer_kernel<<<256, 256, 0, stream>>>(nb, W2, b2, xf, xT);
  bmm_mfma_kernel<<<256, 256, 0, stream>>>(dist, xT, nb);
  layer_kernel<<<256, 256, 0, stream>>>(nb, W3, b3, xf, xT);

  // logits (MFMA f16) + fused mask/tanh/gumbel/T -> y in d_out
  logits_mfma_kernel<<<1024, 256, 0, stream>>>(xf, noise, out);

  // P0 = exp(y - rowmax)  (in place)
  rowexp_kernel<<<BB * NN, 256, 0, stream>>>(out);

  // Sinkhorn (R6 protocol + vote-in-flag early exit)
  const float* P0c = out; float* caccP = cacc; unsigned int* flagsP = flags; float* outP = out;
  void* args[] = {(void*)&P0c, (void*)&caccP, (void*)&flagsP, (void*)&outP};
  hipLaunchCooperativeKernel(reinterpret_cast<void*>(sinkhorn_kernel),
                             dim3(BB * SB), dim3(256), args, 0, stream);
}

// Round 9
// 132.714 us; speedup vs baseline: 2.8278x; 1.1229x over previous
//
#include <hip/hip_runtime.h>

// Problem constants
#define BB 16
#define NN 512
#define HH 128
#define SB 32   // sinkhorn slabs (blocks) per batch
#define RB 16   // sinkhorn rows per slab

#define SCOPE_AGENT __HIP_MEMORY_SCOPE_AGENT

typedef _Float16 f16x8 __attribute__((ext_vector_type(8)));
typedef _Float16 f16x4 __attribute__((ext_vector_type(4)));
typedef float    f32x4 __attribute__((ext_vector_type(4)));

// ---------------------------------------------------------------- embed ----
// writes x0 (f16, [b][n][h]) and x0T (f16, [b][h][n]); also zeroes the
// sinkhorn ctrl region (cacc+flags, 192 KB) -- replaces a 40us rocclr fill.
// Stream order guarantees the zeroes land before sinkhorn (6 kernels later).
__global__ __launch_bounds__(256) void embed16_kernel(
    const float* __restrict__ pts, const float* __restrict__ Wemb,
    const float* __restrict__ bemb, _Float16* __restrict__ xf,
    _Float16* __restrict__ xT, unsigned int* __restrict__ ctrlz)
{
  int idx = blockIdx.x * 256 + threadIdx.x;   // 0 .. B*N*16
  if (idx < 49152) ctrlz[idx] = 0u;           // 192 KB / 4
  int ho = (idx & 15) * 8;                    // h-octet
  int bn = idx >> 4;
  int b = bn >> 9, n = bn & 511;
  float p0 = pts[bn * 2 + 0], p1 = pts[bn * 2 + 1];
  f16x8 h;
  #pragma unroll
  for (int i = 0; i < 8; ++i) {
    float v = fmaf(p0, Wemb[ho + i], fmaf(p1, Wemb[HH + ho + i], bemb[ho + i]));
    h[i] = (_Float16)v;
    xT[((size_t)b * HH + ho + i) * NN + n] = (_Float16)v;
  }
  *reinterpret_cast<f16x8*>(&xf[(size_t)bn * HH + ho]) = h;
}

// ------------------------------------------------------------ bmm (MFMA) ---
// nb[b][512][128] = exp(-dist[b]) @ x[b]   (B operand from xT rows, f16)
__global__ __launch_bounds__(256) void bmm_mfma_kernel(
    const float* __restrict__ dist, const _Float16* __restrict__ xT,
    float* __restrict__ nb)
{
  __shared__ _Float16 Al[32][40];    // row stride 80B -> bank-spread
  __shared__ _Float16 Bl[128][40];
  const int bid = blockIdx.x;
  const int mt = bid & 15, b = bid >> 4;
  const int tid = threadIdx.x;
  const int row0 = mt * 32;
  const float* Ab = dist + ((size_t)b * NN + row0) * NN;
  const _Float16* xTb = xT + (size_t)b * HH * NN;

  const int wv = tid >> 6, lane = tid & 63;
  const int wm = wv >> 1, wn = wv & 1;
  const int fr = lane & 15, fo = lane >> 4;

  f32x4 acc[4] = {};

  for (int k0 = 0; k0 < NN; k0 += 32) {
    {  // stage A: 32 rows x 32 k, f32 -> exp(-x) -> f16
      const int r = tid >> 3, q = tid & 7;
      float4 v = *reinterpret_cast<const float4*>(&Ab[(size_t)r * NN + k0 + q * 4]);
      f16x4 h;
      h[0] = (_Float16)__expf(-v.x); h[1] = (_Float16)__expf(-v.y);
      h[2] = (_Float16)__expf(-v.z); h[3] = (_Float16)__expf(-v.w);
      *reinterpret_cast<f16x4*>(&Al[r][q * 4]) = h;
    }
    {  // stage B: 128 h-rows x 32 k from xT (contig k)
      #pragma unroll
      for (int it = 0; it < 2; ++it) {
        const int slot = it * 256 + tid;
        const int n = slot >> 2, q = slot & 3;
        f16x8 v = *reinterpret_cast<const f16x8*>(&xTb[(size_t)n * NN + k0 + q * 8]);
        *reinterpret_cast<f16x8*>(&Bl[n][q * 8]) = v;
      }
    }
    __syncthreads();
    f16x8 af = *reinterpret_cast<const f16x8*>(&Al[wm * 16 + fr][fo * 8]);
    #pragma unroll
    for (int nt = 0; nt < 4; ++nt) {
      f16x8 bf = *reinterpret_cast<const f16x8*>(&Bl[wn * 64 + nt * 16 + fr][fo * 8]);
      acc[nt] = __builtin_amdgcn_mfma_f32_16x16x32_f16(af, bf, acc[nt], 0, 0, 0);
    }
    __syncthreads();
  }
  float* Cb = nb + ((size_t)b * NN + row0) * HH;
  #pragma unroll
  for (int nt = 0; nt < 4; ++nt) {
    const int col = wn * 64 + nt * 16 + fr;
    #pragma unroll
    for (int m = 0; m < 4; ++m) {
      const int row = wm * 16 + fo * 4 + m;
      Cb[(size_t)row * HH + col] = acc[nt][m];
    }
  }
}

// --------------------------------------------------------- layer (f32) -----
// x = relu(nb @ W + b); M=512,N=128,K=128; writes x f16 rows + xT f16.
constexpr int BMt = 64, BNt = 64, BKt = 32;

__global__ __launch_bounds__(256) void layer_kernel(
    const float* __restrict__ Ag, const float* __restrict__ Bg,
    const float* __restrict__ bias,
    _Float16* __restrict__ xf, _Float16* __restrict__ xT)
{
  const int bid = blockIdx.x;
  const int tn  = bid % 2;
  const int tmi = (bid / 2) % 8;
  const int b   = bid / 16;
  const int tid = threadIdx.x;
  const int row0 = tmi * BMt, col0 = tn * BNt;

  __shared__ float Al[BKt][BMt + 4];
  __shared__ float Bl[BKt][BNt + 4];

  const float* Ab = Ag + (size_t)b * NN * HH;
  const float* Bb = Bg;   // shared weights

  const int rowr = (tid >> 4) * 4;
  const int colr = (tid & 15) * 4;

  float acc[4][4] = {};

  for (int k0 = 0; k0 < HH; k0 += BKt) {
    {
      int r = tid >> 3, kq = (tid & 7) * 4;
      #pragma unroll
      for (int rr = 0; rr < BMt; rr += 32) {
        float4 v = *reinterpret_cast<const float4*>(
            &Ab[(size_t)(row0 + r + rr) * HH + k0 + kq]);
        Al[kq + 0][r + rr] = v.x; Al[kq + 1][r + rr] = v.y;
        Al[kq + 2][r + rr] = v.z; Al[kq + 3][r + rr] = v.w;
      }
    }
    {
      int kk = tid >> 4, nc = (tid & 15) * 4;
      #pragma unroll
      for (int kr = 0; kr < BKt; kr += 16) {
        float4 v = *reinterpret_cast<const float4*>(
            &Bb[(size_t)(k0 + kk + kr) * HH + col0 + nc]);
        *reinterpret_cast<float4*>(&Bl[kk + kr][nc]) = v;
      }
    }
    __syncthreads();
    #pragma unroll
    for (int kk = 0; kk < BKt; ++kk) {
      const float4 a4 = *reinterpret_cast<const float4*>(&Al[kk][rowr]);
      const float4 b4 = *reinterpret_cast<const float4*>(&Bl[kk][colr]);
      const float av[4] = {a4.x, a4.y, a4.z, a4.w};
      const float bw[4] = {b4.x, b4.y, b4.z, b4.w};
      #pragma unroll
      for (int i = 0; i < 4; ++i)
        #pragma unroll
        for (int j = 0; j < 4; ++j)
          acc[i][j] = fmaf(av[i], bw[j], acc[i][j]);
    }
    __syncthreads();
  }

  float vals[4][4];
  #pragma unroll
  for (int i = 0; i < 4; ++i)
    #pragma unroll
    for (int j = 0; j < 4; ++j)
      vals[i][j] = fmaxf(acc[i][j] + bias[col0 + colr + j], 0.0f);

  _Float16* xfb = xf + (size_t)b * NN * HH;
  _Float16* xTb = xT + (size_t)b * HH * NN;
  #pragma unroll
  for (int i = 0; i < 4; ++i) {
    f16x4 hr;
    #pragma unroll
    for (int j = 0; j < 4; ++j) hr[j] = (_Float16)vals[i][j];
    *reinterpret_cast<f16x4*>(&xfb[(size_t)(row0 + rowr + i) * HH + col0 + colr]) = hr;
  }
  #pragma unroll
  for (int j = 0; j < 4; ++j) {
    f16x4 hc;
    #pragma unroll
    for (int i = 0; i < 4; ++i) hc[i] = (_Float16)vals[i][j];
    *reinterpret_cast<f16x4*>(&xTb[(size_t)(col0 + colr + j) * NN + row0 + rowr]) = hc;
  }
}

// --------------------------------------------------------- logits (MFMA) ---
// y[b][i][j] = (10*tanh(x_i . x_j - 1e9*[i==j]) + 0.01*gumbel)/3
__global__ __launch_bounds__(256) void logits_mfma_kernel(
    const _Float16* __restrict__ xf, const float* __restrict__ noise,
    float* __restrict__ y)
{
  __shared__ _Float16 Al[64][136];
  __shared__ _Float16 Bl[64][136];
  const int bid = blockIdx.x;
  const int tn = bid & 7, tm = (bid >> 3) & 7, b = bid >> 6;
  const int row0 = tm * 64, col0 = tn * 64;
  const _Float16* xb = xf + (size_t)b * NN * HH;
  const int tid = threadIdx.x;

  #pragma unroll
  for (int it = 0; it < 4; ++it) {
    const int slot = it * 256 + tid;
    const int r = slot >> 4, q = slot & 15;
    *reinterpret_cast<f16x8*>(&Al[r][q * 8]) =
        *reinterpret_cast<const f16x8*>(&xb[(size_t)(row0 + r) * HH + q * 8]);
    *reinterpret_cast<f16x8*>(&Bl[r][q * 8]) =
        *reinterpret_cast<const f16x8*>(&xb[(size_t)(col0 + r) * HH + q * 8]);
  }
  __syncthreads();

  const int wv = tid >> 6, lane = tid & 63;
  const int wm = wv >> 1, wn = wv & 1;
  const int fr = lane & 15, fo = lane >> 4;
  f32x4 acc[2][2] = {};
  #pragma unroll
  for (int ks = 0; ks < 4; ++ks) {
    f16x8 af[2], bf[2];
    #pragma unroll
    for (int t2 = 0; t2 < 2; ++t2) {
      af[t2] = *reinterpret_cast<const f16x8*>(&Al[wm * 32 + t2 * 16 + fr][ks * 32 + fo * 8]);
      bf[t2] = *reinterpret_cast<const f16x8*>(&Bl[wn * 32 + t2 * 16 + fr][ks * 32 + fo * 8]);
    }
    #pragma unroll
    for (int i = 0; i < 2; ++i)
      #pragma unroll
      for (int j = 0; j < 2; ++j)
        acc[i][j] = __builtin_amdgcn_mfma_f32_16x16x32_f16(af[i], bf[j], acc[i][j], 0, 0, 0);
  }

  float* yb = y + (size_t)b * NN * NN;
  const float* nzb = noise + (size_t)b * NN * NN;
  #pragma unroll
  for (int i = 0; i < 2; ++i) {
    #pragma unroll
    for (int j = 0; j < 2; ++j) {
      const int gj = col0 + wn * 32 + j * 16 + fr;
      #pragma unroll
      for (int m = 0; m < 4; ++m) {
        const int gi = row0 + wm * 32 + i * 16 + fo * 4 + m;
        float s = acc[i][j][m];
        if (gi == gj) s -= 1e9f;
        float th = 1.0f - 2.0f / (__expf(2.0f * s) + 1.0f);    // tanh(s)
        float u  = nzb[(size_t)gi * NN + gj];
        float eps = -__logf(-__logf(u));                        // Gumbel
        yb[(size_t)gi * NN + gj] = (10.0f * th + 0.01f * eps) * (1.0f / 3.0f);
      }
    }
  }
}

// ----------------------------------------------------------- Sinkhorn ------
// R8-proven protocol (32 distributed flags w/ vote-in-flag early exit,
// agent-scope relaxed atomics, delta-trick accumulators) + fused softmax:
// stages RAW y rows (slab holds complete rows), computes rowmax -> exp ->
// rowsum in LDS; the rowsum IS r0 (replaces the first row_update and the
// separate rowexp kernel).
__global__ __launch_bounds__(256) void sinkhorn_kernel(
    const float* __restrict__ Y, float* __restrict__ cacc,
    unsigned int* __restrict__ flags, float* __restrict__ out)
{
  __shared__ float Pl[RB][513];
  __shared__ float cl[512];
  __shared__ float rl[RB];
  __shared__ float red[16][17];
  __shared__ float rmax[RB];
  __shared__ float wmax[4];
  __shared__ int stopf;

  const int bid = blockIdx.x;
  const int b = bid >> 5, s = bid & 31;
  const int tid = threadIdx.x;
  const float* Yb = Y + ((size_t)b * NN + s * RB) * NN;

  // stage raw y slab
  for (int f = tid; f < RB * 128; f += 256) {
    int r = f >> 7, c4 = (f & 127) * 4;
    float4 v = *reinterpret_cast<const float4*>(&Yb[(size_t)r * NN + c4]);
    Pl[r][c4 + 0] = v.x; Pl[r][c4 + 1] = v.y;
    Pl[r][c4 + 2] = v.z; Pl[r][c4 + 3] = v.w;
  }
  cl[tid] = 1.0f; cl[tid + 256] = 1.0f;
  __syncthreads();

  // fused rowmax -> exp -> rowsum (i = row, ch = 32-col chunk; 8*ch bank
  // stagger -> <=2-way conflicts). rl = 1/rowsum = softmax fold (r0).
  {
    const int i = tid & 15, ch = tid >> 4;
    float mx = -1e30f;
    #pragma unroll
    for (int q = 0; q < 32; ++q) {
      const int j = ch * 32 + ((q + ch * 8) & 31);
      mx = fmaxf(mx, Pl[i][j]);
    }
    red[ch][i] = mx;
    __syncthreads();
    if (tid < RB) {
      float m2 = -1e30f;
      #pragma unroll
      for (int q = 0; q < 16; ++q) m2 = fmaxf(m2, red[q][tid]);
      rmax[tid] = m2;
    }
    __syncthreads();
    const float rm = rmax[i];
    float sum = 0.0f;
    #pragma unroll
    for (int q = 0; q < 32; ++q) {
      const int j = ch * 32 + ((q + ch * 8) & 31);
      float e = __expf(Pl[i][j] - rm);
      Pl[i][j] = e;
      sum += e;
    }
    red[ch][i] = sum;
    __syncthreads();
    if (tid < RB) {
      float v = 0.0f;
      #pragma unroll
      for (int q = 0; q < 16; ++q) v += red[q][tid];
      rl[tid] = 1.0f / v;
    }
    __syncthreads();
  }

  auto row_update = [&]() {
    const int i = tid & 15, ch = tid >> 4;
    const int j0 = ch * 32, st = (ch * 8) & 31;
    float p = 0.0f;
    #pragma unroll
    for (int q = 0; q < 32; ++q) {
      const int j = j0 + ((q + st) & 31);
      p = fmaf(Pl[i][j], cl[j], p);
    }
    red[ch][i] = p;
    __syncthreads();
    if (tid < RB) {
      float v = 0.0f;
      #pragma unroll
      for (int q = 0; q < 16; ++q) v += red[q][tid];
      rl[tid] = 1.0f / v;
    }
    __syncthreads();
  };

  unsigned int* myflag = flags + (size_t)(b * SB + s) * 64;
  float* ca0 = cacc + (size_t)b * 512;
  float* ca1 = cacc + (size_t)(BB + b) * 512;
  float pA0 = 0.f, pA1 = 0.f, pB0 = 0.f, pB1 = 0.f;
  unsigned int convbit = 0;

  for (int it = 0; it < 60; ++it) {
    float* ca  = (it & 1) ? ca1 : ca0;
    float& pv0 = (it & 1) ? pB0 : pA0;
    float& pv1 = (it & 1) ? pB1 : pA1;

    // phase A: partial column sums of diag(r)P0 over this slab -> atomicAdd
    float u0 = 0.0f, u1 = 0.0f;
    #pragma unroll
    for (int i2 = 0; i2 < RB; ++i2) {
      const float rv = rl[i2];
      u0 = fmaf(Pl[i2][tid],       rv, u0);
      u1 = fmaf(Pl[i2][tid + 256], rv, u1);
    }
    __hip_atomic_fetch_add(&ca[tid],       u0 - pv0, __ATOMIC_RELAXED, SCOPE_AGENT);
    __hip_atomic_fetch_add(&ca[tid + 256], u1 - pv1, __ATOMIC_RELAXED, SCOPE_AGENT);
    pv0 = u0; pv1 = u1;
    __syncthreads();  // vmcnt(0): this block's adds acked at coherence point

    // arrive: monotonic flag carries the convergence vote in bit 0
    if (tid == 0)
      __hip_atomic_store(myflag, ((unsigned int)(it + 1) << 1) | convbit,
                         __ATOMIC_RELAXED, SCOPE_AGENT);
    // wait (wave 0): 32 lanes poll the 32 flags; AND the votes via ballot
    if (tid < 64) {
      unsigned int v = 3u;              // lanes 32..63: arrived + vote yes
      if (tid < SB) {
        const unsigned int* fp = flags + (size_t)(b * SB + tid) * 64;
        do {
          v = __hip_atomic_load(fp, __ATOMIC_RELAXED, SCOPE_AGENT);
          if ((v >> 1) >= (unsigned int)(it + 1)) break;
          __builtin_amdgcn_s_sleep(1);
        } while (true);
      }
      unsigned long long m = __ballot((v & 1u) != 0u);
      if (tid == 0) stopf = ((m & 0xFFFFFFFFull) == 0xFFFFFFFFull) ? 1 : 0;
    }
    __syncthreads();
    if (stopf) break;   // unanimous: derived from the same 32 published words

    // phase B: read summed colsums; measure dm; update c; row pass
    float t0 = __hip_atomic_load(&ca[tid],       __ATOMIC_RELAXED, SCOPE_AGENT);
    float t1 = __hip_atomic_load(&ca[tid + 256], __ATOMIC_RELAXED, SCOPE_AGENT);
    float d = fmaxf(fabsf(fmaf(t0, cl[tid], -1.0f)),
                    fabsf(fmaf(t1, cl[tid + 256], -1.0f)));
    #pragma unroll
    for (int off = 32; off >= 1; off >>= 1) d = fmaxf(d, __shfl_xor(d, off));
    if ((tid & 63) == 0) wmax[tid >> 6] = d;
    cl[tid] = 1.0f / t0; cl[tid + 256] = 1.0f / t1;
    __syncthreads();
    const float dm = fmaxf(fmaxf(wmax[0], wmax[1]), fmaxf(wmax[2], wmax[3]));
    convbit = (dm < 1e-5f) ? 1u : 0u;
    row_update();
  }

  // final: out = r_i * P0_ij * c_j   (reads LDS only)
  float* Ob = out + ((size_t)b * NN + s * RB) * NN;
  #pragma unroll
  for (int i = 0; i < RB; ++i) {
    const float rv = rl[i];
    Ob[(size_t)i * NN + tid]       = rv * Pl[i][tid]       * cl[tid];
    Ob[(size_t)i * NN + tid + 256] = rv * Pl[i][tid + 256] * cl[tid + 256];
  }
}

// ------------------------------------------------------------- launch ------
extern "C" void kernel_launch(void* const* d_in, const int* in_sizes, int n_in,
                              void* d_out, int out_size, void* d_ws, size_t ws_size,
                              hipStream_t stream)
{
  const float* points = (const float*)d_in[0];
  const float* dist   = (const float*)d_in[1];
  const float* noise  = (const float*)d_in[2];
  const float* Wemb   = (const float*)d_in[3];
  const float* bemb   = (const float*)d_in[4];
  const float* W1 = (const float*)d_in[5]; const float* b1 = (const float*)d_in[6];
  const float* W2 = (const float*)d_in[7]; const float* b2 = (const float*)d_in[8];
  const float* W3 = (const float*)d_in[9]; const float* b3 = (const float*)d_in[10];
  float* out = (float*)d_out;

  char* ws = (char*)d_ws;                             // ws_size = 256 MiB
  float*     nb = (float*)ws;                         // 4 MB
  _Float16*  xf = (_Float16*)(ws + (4u << 20));       // 2 MB
  _Float16*  xT = (_Float16*)(ws + (6u << 20));       // 2 MB
  char* ctrl = ws + (8u << 20);
  float*        cacc  = (float*)ctrl;                 // 64 KB
  unsigned int* flags = (unsigned int*)(ctrl + (64u << 10));  // 128 KB

  // embed -> x0 f16 + x0T f16 ; also zeroes ctrl (192 KB)
  embed16_kernel<<<512, 256, 0, stream>>>(points, Wemb, bemb, xf, xT,
                                          (unsigned int*)ctrl);

  // 3 GCN layers: nb = exp(-dist) @ x (MFMA f16); x = relu(nb@W+b) (f32)
  bmm_mfma_kernel<<<256, 256, 0, stream>>>(dist, xT, nb);
  layer_kernel<<<256, 256, 0, stream>>>(nb, W1, b1, xf, xT);
  bmm_mfma_kernel<<<256, 256, 0, stream>>>(dist, xT, nb);
  layer_kernel<<<256, 256, 0, stream>>>(nb, W2, b2, xf, xT);
  bmm_mfma_kernel<<<256, 256, 0, stream>>>(dist, xT, nb);
  layer_kernel<<<256, 256, 0, stream>>>(nb, W3, b3, xf, xT);

  // logits (MFMA f16) + fused mask/tanh/gumbel/T -> y in d_out
  logits_mfma_kernel<<<1024, 256, 0, stream>>>(xf, noise, out);

  // Sinkhorn (R8 protocol + fused rowmax/exp/rowsum staging)
  const float* Yc = out; float* caccP = cacc; unsigned int* flagsP = flags; float* outP = out;
  void* args[] = {(void*)&Yc, (void*)&caccP, (void*)&flagsP, (void*)&outP};
  hipLaunchCooperativeKernel(reinterpret_cast<void*>(sinkhorn_kernel),
                             dim3(BB * SB), dim3(256), args, 0, stream);
}

// Round 13
// 103.230 us; speedup vs baseline: 3.6355x; 1.2856x over previous
//
#include <hip/hip_runtime.h>

// Problem constants
#define BB 16
#define NN 512
#define HH 128
#define SB 32   // sinkhorn slabs (blocks) per batch
#define RB 16   // sinkhorn rows per slab

#define SCOPE_AGENT __HIP_MEMORY_SCOPE_AGENT

typedef _Float16 f16x8 __attribute__((ext_vector_type(8)));
typedef _Float16 f16x4 __attribute__((ext_vector_type(4)));
typedef float    f32x4 __attribute__((ext_vector_type(4)));

// ------------------------------------------------------------ fused GCN ----
// One kernel = bmm (exp(-dist) @ x, MFMA f16) + layer (relu(nb@W+b)).
// FIX (R12->R13): nb parked in Cl SCALED by 2^-10. nb = sum_512 adj*x with
// adj>0, x>=0 (relu) has no cancellation -> nb reaches ~1e5 > f16 max ->
// Inf -> NaN in phase 2 -> fmaxf(NaN,0)=0 laundered it to finite garbage.
// Range proof: x <= 65504 (f16-stored, R9-proven) -> nb <= 512*65504=3.4e7
// -> scaled <= 3.3e4 < 65504. Power-of-2 scale = exact; precision unchanged.
template <bool EMB>
__global__ __launch_bounds__(256) void gcn_kernel(
    const float* __restrict__ dist, const _Float16* __restrict__ xTin,
    const float* __restrict__ pts, const float* __restrict__ Wemb,
    const float* __restrict__ bemb,
    const float* __restrict__ W, const float* __restrict__ bias,
    _Float16* __restrict__ xfout, _Float16* __restrict__ xTout,
    unsigned int* __restrict__ ctrlz)
{
  __shared__ _Float16 Al[32][40];     // adj tile (f16), bank-spread
  __shared__ _Float16 Bl[128][40];    // x^T tile
  __shared__ _Float16 Cl[32][136];    // nb tile * 2^-10 (phase-1 result)
  __shared__ _Float16 Wl[128][136];   // W transposed: Wl[n][k] = W[k][n]

  const int bid = blockIdx.x;
  const int mt = bid & 15, b = bid >> 4;
  const int tid = threadIdx.x;
  const int row0 = mt * 32;

  if (EMB) {  // fold ctrl zeroing into layer 1 (stream-ordered)
    int idx = bid * 256 + tid;
    if (idx < 49152) ctrlz[idx] = 0u;
  }

  // stage W transposed (128x128 = 16384 elems / 256 thr = 64 reps)
  #pragma unroll
  for (int rep = 0; rep < 64; ++rep) {
    const int idx = rep * 256 + tid;
    const int k = idx >> 7, n = idx & 127;
    Wl[n][k] = (_Float16)W[(size_t)k * HH + n];
  }

  const float* Ab = dist + ((size_t)b * NN + row0) * NN;
  const _Float16* xTb = EMB ? nullptr : (xTin + (size_t)b * HH * NN);

  const int wv = tid >> 6, lane = tid & 63;
  const int wm = wv >> 1, wn = wv & 1;
  const int fr = lane & 15, fo = lane >> 4;

  // EMB: hoist per-h weights (thread handles h-rows n0 and n0+64)
  float we0a = 0.f, we1a = 0.f, ba = 0.f, we0b = 0.f, we1b = 0.f, bb2 = 0.f;
  const int n0 = tid >> 2, q4 = tid & 3;
  if (EMB) {
    we0a = Wemb[n0];      we1a = Wemb[HH + n0];      ba  = bemb[n0];
    we0b = Wemb[n0 + 64]; we1b = Wemb[HH + n0 + 64]; bb2 = bemb[n0 + 64];
  }

  f32x4 acc[4] = {};

  for (int k0 = 0; k0 < NN; k0 += 32) {
    {  // stage A: 32 rows x 32 k, f32 -> exp(-x) -> f16
      const int r = tid >> 3, q = tid & 7;
      float4 v = *reinterpret_cast<const float4*>(&Ab[(size_t)r * NN + k0 + q * 4]);
      f16x4 h;
      h[0] = (_Float16)__expf(-v.x); h[1] = (_Float16)__expf(-v.y);
      h[2] = (_Float16)__expf(-v.z); h[3] = (_Float16)__expf(-v.w);
      *reinterpret_cast<f16x4*>(&Al[r][q * 4]) = h;
    }
    if (!EMB) {  // stage B from xT rows (contig k)
      #pragma unroll
      for (int it = 0; it < 2; ++it) {
        const int slot = it * 256 + tid;
        const int n = slot >> 2, q = slot & 3;
        f16x8 v = *reinterpret_cast<const f16x8*>(&xTb[(size_t)n * NN + k0 + q * 8]);
        *reinterpret_cast<f16x8*>(&Bl[n][q * 8]) = v;
      }
    } else {     // stage B = x0^T computed on the fly
      float2 pv[8];
      #pragma unroll
      for (int e = 0; e < 8; ++e)
        pv[e] = *reinterpret_cast<const float2*>(
            &pts[((size_t)b * NN + k0 + q4 * 8 + e) * 2]);
      f16x8 va, vb;
      #pragma unroll
      for (int e = 0; e < 8; ++e) {
        va[e] = (_Float16)fmaf(pv[e].x, we0a, fmaf(pv[e].y, we1a, ba));
        vb[e] = (_Float16)fmaf(pv[e].x, we0b, fmaf(pv[e].y, we1b, bb2));
      }
      *reinterpret_cast<f16x8*>(&Bl[n0][q4 * 8]) = va;
      *reinterpret_cast<f16x8*>(&Bl[n0 + 64][q4 * 8]) = vb;
    }
    __syncthreads();
    f16x8 af = *reinterpret_cast<const f16x8*>(&Al[wm * 16 + fr][fo * 8]);
    #pragma unroll
    for (int nt = 0; nt < 4; ++nt) {
      f16x8 bf = *reinterpret_cast<const f16x8*>(&Bl[wn * 64 + nt * 16 + fr][fo * 8]);
      acc[nt] = __builtin_amdgcn_mfma_f32_16x16x32_f16(af, bf, acc[nt], 0, 0, 0);
    }
    __syncthreads();
  }

  // park nb tile in LDS, scaled 2^-10 (exact) to stay inside f16 range
  #pragma unroll
  for (int nt = 0; nt < 4; ++nt) {
    const int col = wn * 64 + nt * 16 + fr;
    #pragma unroll
    for (int m = 0; m < 4; ++m)
      Cl[wm * 16 + fo * 4 + m][col] = (_Float16)(acc[nt][m] * 0x1p-10f);
  }
  __syncthreads();

  // phase 2: out = relu((nb_scaled @ W) * 2^10 + bias)
  f32x4 acc2[4] = {};
  #pragma unroll
  for (int ks = 0; ks < 4; ++ks) {
    f16x8 af2 = *reinterpret_cast<const f16x8*>(&Cl[wm * 16 + fr][ks * 32 + fo * 8]);
    #pragma unroll
    for (int nt = 0; nt < 4; ++nt) {
      f16x8 bf2 = *reinterpret_cast<const f16x8*>(&Wl[wn * 64 + nt * 16 + fr][ks * 32 + fo * 8]);
      acc2[nt] = __builtin_amdgcn_mfma_f32_16x16x32_f16(af2, bf2, acc2[nt], 0, 0, 0);
    }
  }

  _Float16* xfb = xfout + (size_t)b * NN * HH;
  _Float16* xTb2 = xTout + (size_t)b * HH * NN;
  #pragma unroll
  for (int nt = 0; nt < 4; ++nt) {
    const int col = wn * 64 + nt * 16 + fr;
    const float bv = bias[col];
    const int rowb = row0 + wm * 16 + fo * 4;
    f16x4 hc;
    #pragma unroll
    for (int m = 0; m < 4; ++m) {
      float v = fmaxf(fmaf(acc2[nt][m], 1024.0f, bv), 0.0f);
      hc[m] = (_Float16)v;
      xfb[(size_t)(rowb + m) * HH + col] = (_Float16)v;
    }
    *reinterpret_cast<f16x4*>(&xTb2[(size_t)col * NN + rowb]) = hc;
  }
}

// --------------------------------------------------------- logits (MFMA) ---
// R9-PROVEN, byte-identical. y = (10*tanh(x_i.x_j - 1e9*diag) + gumbel)/3.
__global__ __launch_bounds__(256) void logits_mfma_kernel(
    const _Float16* __restrict__ xf, const float* __restrict__ noise,
    float* __restrict__ y)
{
  __shared__ _Float16 Al[64][136];
  __shared__ _Float16 Bl[64][136];
  const int bid = blockIdx.x;
  const int tn = bid & 7, tm = (bid >> 3) & 7, b = bid >> 6;
  const int row0 = tm * 64, col0 = tn * 64;
  const _Float16* xb = xf + (size_t)b * NN * HH;
  const int tid = threadIdx.x;

  #pragma unroll
  for (int it = 0; it < 4; ++it) {
    const int slot = it * 256 + tid;
    const int r = slot >> 4, q = slot & 15;
    *reinterpret_cast<f16x8*>(&Al[r][q * 8]) =
        *reinterpret_cast<const f16x8*>(&xb[(size_t)(row0 + r) * HH + q * 8]);
    *reinterpret_cast<f16x8*>(&Bl[r][q * 8]) =
        *reinterpret_cast<const f16x8*>(&xb[(size_t)(col0 + r) * HH + q * 8]);
  }
  __syncthreads();

  const int wv = tid >> 6, lane = tid & 63;
  const int wm = wv >> 1, wn = wv & 1;
  const int fr = lane & 15, fo = lane >> 4;
  f32x4 acc[2][2] = {};
  #pragma unroll
  for (int ks = 0; ks < 4; ++ks) {
    f16x8 af[2], bf[2];
    #pragma unroll
    for (int t2 = 0; t2 < 2; ++t2) {
      af[t2] = *reinterpret_cast<const f16x8*>(&Al[wm * 32 + t2 * 16 + fr][ks * 32 + fo * 8]);
      bf[t2] = *reinterpret_cast<const f16x8*>(&Bl[wn * 32 + t2 * 16 + fr][ks * 32 + fo * 8]);
    }
    #pragma unroll
    for (int i = 0; i < 2; ++i)
      #pragma unroll
      for (int j = 0; j < 2; ++j)
        acc[i][j] = __builtin_amdgcn_mfma_f32_16x16x32_f16(af[i], bf[j], acc[i][j], 0, 0, 0);
  }

  float* yb = y + (size_t)b * NN * NN;
  const float* nzb = noise + (size_t)b * NN * NN;
  #pragma unroll
  for (int i = 0; i < 2; ++i) {
    #pragma unroll
    for (int j = 0; j < 2; ++j) {
      const int gj = col0 + wn * 32 + j * 16 + fr;
      #pragma unroll
      for (int m = 0; m < 4; ++m) {
        const int gi = row0 + wm * 32 + i * 16 + fo * 4 + m;
        float s = acc[i][j][m];
        if (gi == gj) s -= 1e9f;
        float th = 1.0f - 2.0f / (__expf(2.0f * s) + 1.0f);    // tanh(s)
        float u  = nzb[(size_t)gi * NN + gj];
        float eps = -__logf(-__logf(u));                        // Gumbel
        yb[(size_t)gi * NN + gj] = (10.0f * th + 0.01f * eps) * (1.0f / 3.0f);
      }
    }
  }
}

// ----------------------------------------------------------- Sinkhorn ------
// R9-PROVEN, byte-identical (fused rowmax/exp/rowsum staging of y, 32
// distributed flags w/ vote-in-flag early exit, agent-scope relaxed atomics,
// delta-trick accumulators).
__global__ __launch_bounds__(256) void sinkhorn_kernel(
    const float* __restrict__ Y, float* __restrict__ cacc,
    unsigned int* __restrict__ flags, float* __restrict__ out)
{
  __shared__ float Pl[RB][513];
  __shared__ float cl[512];
  __shared__ float rl[RB];
  __shared__ float red[16][17];
  __shared__ float rmax[RB];
  __shared__ float wmax[4];
  __shared__ int stopf;

  const int bid = blockIdx.x;
  const int b = bid >> 5, s = bid & 31;
  const int tid = threadIdx.x;
  const float* Yb = Y + ((size_t)b * NN + s * RB) * NN;

  for (int f = tid; f < RB * 128; f += 256) {
    int r = f >> 7, c4 = (f & 127) * 4;
    float4 v = *reinterpret_cast<const float4*>(&Yb[(size_t)r * NN + c4]);
    Pl[r][c4 + 0] = v.x; Pl[r][c4 + 1] = v.y;
    Pl[r][c4 + 2] = v.z; Pl[r][c4 + 3] = v.w;
  }
  cl[tid] = 1.0f; cl[tid + 256] = 1.0f;
  __syncthreads();

  // fused rowmax -> exp -> rowsum; rl = 1/rowsum (softmax fold, r0)
  {
    const int i = tid & 15, ch = tid >> 4;
    float mx = -1e30f;
    #pragma unroll
    for (int q = 0; q < 32; ++q) {
      const int j = ch * 32 + ((q + ch * 8) & 31);
      mx = fmaxf(mx, Pl[i][j]);
    }
    red[ch][i] = mx;
    __syncthreads();
    if (tid < RB) {
      float m2 = -1e30f;
      #pragma unroll
      for (int q = 0; q < 16; ++q) m2 = fmaxf(m2, red[q][tid]);
      rmax[tid] = m2;
    }
    __syncthreads();
    const float rm = rmax[i];
    float sum = 0.0f;
    #pragma unroll
    for (int q = 0; q < 32; ++q) {
      const int j = ch * 32 + ((q + ch * 8) & 31);
      float e = __expf(Pl[i][j] - rm);
      Pl[i][j] = e;
      sum += e;
    }
    red[ch][i] = sum;
    __syncthreads();
    if (tid < RB) {
      float v = 0.0f;
      #pragma unroll
      for (int q = 0; q < 16; ++q) v += red[q][tid];
      rl[tid] = 1.0f / v;
    }
    __syncthreads();
  }

  auto row_update = [&]() {
    const int i = tid & 15, ch = tid >> 4;
    const int j0 = ch * 32, st = (ch * 8) & 31;
    float p = 0.0f;
    #pragma unroll
    for (int q = 0; q < 32; ++q) {
      const int j = j0 + ((q + st) & 31);
      p = fmaf(Pl[i][j], cl[j], p);
    }
    red[ch][i] = p;
    __syncthreads();
    if (tid < RB) {
      float v = 0.0f;
      #pragma unroll
      for (int q = 0; q < 16; ++q) v += red[q][tid];
      rl[tid] = 1.0f / v;
    }
    __syncthreads();
  };

  unsigned int* myflag = flags + (size_t)(b * SB + s) * 64;
  float* ca0 = cacc + (size_t)b * 512;
  float* ca1 = cacc + (size_t)(BB + b) * 512;
  float pA0 = 0.f, pA1 = 0.f, pB0 = 0.f, pB1 = 0.f;
  unsigned int convbit = 0;

  for (int it = 0; it < 60; ++it) {
    float* ca  = (it & 1) ? ca1 : ca0;
    float& pv0 = (it & 1) ? pB0 : pA0;
    float& pv1 = (it & 1) ? pB1 : pA1;

    float u0 = 0.0f, u1 = 0.0f;
    #pragma unroll
    for (int i2 = 0; i2 < RB; ++i2) {
      const float rv = rl[i2];
      u0 = fmaf(Pl[i2][tid],       rv, u0);
      u1 = fmaf(Pl[i2][tid + 256], rv, u1);
    }
    __hip_atomic_fetch_add(&ca[tid],       u0 - pv0, __ATOMIC_RELAXED, SCOPE_AGENT);
    __hip_atomic_fetch_add(&ca[tid + 256], u1 - pv1, __ATOMIC_RELAXED, SCOPE_AGENT);
    pv0 = u0; pv1 = u1;
    __syncthreads();  // vmcnt(0): adds acked at coherence point

    if (tid == 0)
      __hip_atomic_store(myflag, ((unsigned int)(it + 1) << 1) | convbit,
                         __ATOMIC_RELAXED, SCOPE_AGENT);
    if (tid < 64) {
      unsigned int v = 3u;
      if (tid < SB) {
        const unsigned int* fp = flags + (size_t)(b * SB + tid) * 64;
        do {
          v = __hip_atomic_load(fp, __ATOMIC_RELAXED, SCOPE_AGENT);
          if ((v >> 1) >= (unsigned int)(it + 1)) break;
          __builtin_amdgcn_s_sleep(1);
        } while (true);
      }
      unsigned long long m = __ballot((v & 1u) != 0u);
      if (tid == 0) stopf = ((m & 0xFFFFFFFFull) == 0xFFFFFFFFull) ? 1 : 0;
    }
    __syncthreads();
    if (stopf) break;

    float t0 = __hip_atomic_load(&ca[tid],       __ATOMIC_RELAXED, SCOPE_AGENT);
    float t1 = __hip_atomic_load(&ca[tid + 256], __ATOMIC_RELAXED, SCOPE_AGENT);
    float d = fmaxf(fabsf(fmaf(t0, cl[tid], -1.0f)),
                    fabsf(fmaf(t1, cl[tid + 256], -1.0f)));
    #pragma unroll
    for (int off = 32; off >= 1; off >>= 1) d = fmaxf(d, __shfl_xor(d, off));
    if ((tid & 63) == 0) wmax[tid >> 6] = d;
    cl[tid] = 1.0f / t0; cl[tid + 256] = 1.0f / t1;
    __syncthreads();
    const float dm = fmaxf(fmaxf(wmax[0], wmax[1]), fmaxf(wmax[2], wmax[3]));
    convbit = (dm < 1e-5f) ? 1u : 0u;
    row_update();
  }

  float* Ob = out + ((size_t)b * NN + s * RB) * NN;
  #pragma unroll
  for (int i = 0; i < RB; ++i) {
    const float rv = rl[i];
    Ob[(size_t)i * NN + tid]       = rv * Pl[i][tid]       * cl[tid];
    Ob[(size_t)i * NN + tid + 256] = rv * Pl[i][tid + 256] * cl[tid + 256];
  }
}

// ------------------------------------------------------------- launch ------
extern "C" void kernel_launch(void* const* d_in, const int* in_sizes, int n_in,
                              void* d_out, int out_size, void* d_ws, size_t ws_size,
                              hipStream_t stream)
{
  const float* points = (const float*)d_in[0];
  const float* dist   = (const float*)d_in[1];
  const float* noise  = (const float*)d_in[2];
  const float* Wemb   = (const float*)d_in[3];
  const float* bemb   = (const float*)d_in[4];
  const float* W1 = (const float*)d_in[5]; const float* b1 = (const float*)d_in[6];
  const float* W2 = (const float*)d_in[7]; const float* b2 = (const float*)d_in[8];
  const float* W3 = (const float*)d_in[9]; const float* b3 = (const float*)d_in[10];
  float* out = (float*)d_out;

  char* ws = (char*)d_ws;                              // ws_size = 256 MiB
  _Float16* xfA = (_Float16*)ws;                       // 2 MB
  _Float16* xTA = (_Float16*)(ws + (2u << 20));        // 2 MB
  _Float16* xfB = (_Float16*)(ws + (4u << 20));        // 2 MB
  _Float16* xTB = (_Float16*)(ws + (6u << 20));        // 2 MB
  char* ctrl = ws + (8u << 20);
  float*        cacc  = (float*)ctrl;                  // 64 KB
  unsigned int* flags = (unsigned int*)(ctrl + (64u << 10));  // 128 KB

  // 3 fused GCN layers (layer 1 embeds on the fly + zeroes ctrl)
  gcn_kernel<true><<<256, 256, 0, stream>>>(dist, nullptr, points, Wemb, bemb,
                                            W1, b1, xfA, xTA, (unsigned int*)ctrl);
  gcn_kernel<false><<<256, 256, 0, stream>>>(dist, xTA, nullptr, nullptr, nullptr,
                                             W2, b2, xfB, xTB, nullptr);
  gcn_kernel<false><<<256, 256, 0, stream>>>(dist, xTB, nullptr, nullptr, nullptr,
                                             W3, b3, xfA, xTA, nullptr);

  // logits (R9-proven) -> y in d_out
  logits_mfma_kernel<<<1024, 256, 0, stream>>>(xfA, noise, out);

  // Sinkhorn (R9-proven: fused rowexp staging + early exit)
  const float* Yc = out; float* caccP = cacc; unsigned int* flagsP = flags; float* outP = out;
  void* args[] = {(void*)&Yc, (void*)&caccP, (void*)&flagsP, (void*)&outP};
  hipLaunchCooperativeKernel(reinterpret_cast<void*>(sinkhorn_kernel),
                             dim3(BB * SB), dim3(256), args, 0, stream);
}

// Round 14
// 96.192 us; speedup vs baseline: 3.9015x; 1.0732x over previous
//
#include <hip/hip_runtime.h>

// Problem constants
#define BB 16
#define NN 512
#define HH 128
#define SB 32   // sinkhorn slabs (blocks) per batch
#define RB 16   // sinkhorn rows per slab

#define SCOPE_AGENT __HIP_MEMORY_SCOPE_AGENT

typedef _Float16 f16x8 __attribute__((ext_vector_type(8)));
typedef _Float16 f16x4 __attribute__((ext_vector_type(4)));
typedef float    f32x4 __attribute__((ext_vector_type(4)));

// ------------------------------------------------------------ fused GCN ----
// R13-PROVEN. bmm (exp(-dist)@x, MFMA f16) + layer (relu(nb@W+b)); nb parked
// in Cl scaled 2^-10 (f16 range proof: nb <= 512*65504*1 = 3.4e7 -> scaled
// 3.3e4 < 65504; power-of-2 = exact). EMB=true embeds x0 on the fly and
// zeroes the sinkhorn ctrl region.
template <bool EMB>
__global__ __launch_bounds__(256) void gcn_kernel(
    const float* __restrict__ dist, const _Float16* __restrict__ xTin,
    const float* __restrict__ pts, const float* __restrict__ Wemb,
    const float* __restrict__ bemb,
    const float* __restrict__ W, const float* __restrict__ bias,
    _Float16* __restrict__ xfout, _Float16* __restrict__ xTout,
    unsigned int* __restrict__ ctrlz)
{
  __shared__ _Float16 Al[32][40];     // adj tile (f16), bank-spread
  __shared__ _Float16 Bl[128][40];    // x^T tile
  __shared__ _Float16 Cl[32][136];    // nb tile * 2^-10 (phase-1 result)
  __shared__ _Float16 Wl[128][136];   // W transposed: Wl[n][k] = W[k][n]

  const int bid = blockIdx.x;
  const int mt = bid & 15, b = bid >> 4;
  const int tid = threadIdx.x;
  const int row0 = mt * 32;

  if (EMB) {  // fold ctrl zeroing into layer 1 (stream-ordered)
    int idx = bid * 256 + tid;
    if (idx < 49152) ctrlz[idx] = 0u;
  }

  // stage W transposed (128x128 = 16384 elems / 256 thr = 64 reps)
  #pragma unroll
  for (int rep = 0; rep < 64; ++rep) {
    const int idx = rep * 256 + tid;
    const int k = idx >> 7, n = idx & 127;
    Wl[n][k] = (_Float16)W[(size_t)k * HH + n];
  }

  const float* Ab = dist + ((size_t)b * NN + row0) * NN;
  const _Float16* xTb = EMB ? nullptr : (xTin + (size_t)b * HH * NN);

  const int wv = tid >> 6, lane = tid & 63;
  const int wm = wv >> 1, wn = wv & 1;
  const int fr = lane & 15, fo = lane >> 4;

  // EMB: hoist per-h weights (thread handles h-rows n0 and n0+64)
  float we0a = 0.f, we1a = 0.f, ba = 0.f, we0b = 0.f, we1b = 0.f, bb2 = 0.f;
  const int n0 = tid >> 2, q4 = tid & 3;
  if (EMB) {
    we0a = Wemb[n0];      we1a = Wemb[HH + n0];      ba  = bemb[n0];
    we0b = Wemb[n0 + 64]; we1b = Wemb[HH + n0 + 64]; bb2 = bemb[n0 + 64];
  }

  f32x4 acc[4] = {};

  for (int k0 = 0; k0 < NN; k0 += 32) {
    {  // stage A: 32 rows x 32 k, f32 -> exp(-x) -> f16
      const int r = tid >> 3, q = tid & 7;
      float4 v = *reinterpret_cast<const float4*>(&Ab[(size_t)r * NN + k0 + q * 4]);
      f16x4 h;
      h[0] = (_Float16)__expf(-v.x); h[1] = (_Float16)__expf(-v.y);
      h[2] = (_Float16)__expf(-v.z); h[3] = (_Float16)__expf(-v.w);
      *reinterpret_cast<f16x4*>(&Al[r][q * 4]) = h;
    }
    if (!EMB) {  // stage B from xT rows (contig k)
      #pragma unroll
      for (int it = 0; it < 2; ++it) {
        const int slot = it * 256 + tid;
        const int n = slot >> 2, q = slot & 3;
        f16x8 v = *reinterpret_cast<const f16x8*>(&xTb[(size_t)n * NN + k0 + q * 8]);
        *reinterpret_cast<f16x8*>(&Bl[n][q * 8]) = v;
      }
    } else {     // stage B = x0^T computed on the fly
      float2 pv[8];
      #pragma unroll
      for (int e = 0; e < 8; ++e)
        pv[e] = *reinterpret_cast<const float2*>(
            &pts[((size_t)b * NN + k0 + q4 * 8 + e) * 2]);
      f16x8 va, vb;
      #pragma unroll
      for (int e = 0; e < 8; ++e) {
        va[e] = (_Float16)fmaf(pv[e].x, we0a, fmaf(pv[e].y, we1a, ba));
        vb[e] = (_Float16)fmaf(pv[e].x, we0b, fmaf(pv[e].y, we1b, bb2));
      }
      *reinterpret_cast<f16x8*>(&Bl[n0][q4 * 8]) = va;
      *reinterpret_cast<f16x8*>(&Bl[n0 + 64][q4 * 8]) = vb;
    }
    __syncthreads();
    f16x8 af = *reinterpret_cast<const f16x8*>(&Al[wm * 16 + fr][fo * 8]);
    #pragma unroll
    for (int nt = 0; nt < 4; ++nt) {
      f16x8 bf = *reinterpret_cast<const f16x8*>(&Bl[wn * 64 + nt * 16 + fr][fo * 8]);
      acc[nt] = __builtin_amdgcn_mfma_f32_16x16x32_f16(af, bf, acc[nt], 0, 0, 0);
    }
    __syncthreads();
  }

  // park nb tile in LDS, scaled 2^-10 (exact) to stay inside f16 range
  #pragma unroll
  for (int nt = 0; nt < 4; ++nt) {
    const int col = wn * 64 + nt * 16 + fr;
    #pragma unroll
    for (int m = 0; m < 4; ++m)
      Cl[wm * 16 + fo * 4 + m][col] = (_Float16)(acc[nt][m] * 0x1p-10f);
  }
  __syncthreads();

  // phase 2: out = relu((nb_scaled @ W) * 2^10 + bias)
  f32x4 acc2[4] = {};
  #pragma unroll
  for (int ks = 0; ks < 4; ++ks) {
    f16x8 af2 = *reinterpret_cast<const f16x8*>(&Cl[wm * 16 + fr][ks * 32 + fo * 8]);
    #pragma unroll
    for (int nt = 0; nt < 4; ++nt) {
      f16x8 bf2 = *reinterpret_cast<const f16x8*>(&Wl[wn * 64 + nt * 16 + fr][ks * 32 + fo * 8]);
      acc2[nt] = __builtin_amdgcn_mfma_f32_16x16x32_f16(af2, bf2, acc2[nt], 0, 0, 0);
    }
  }

  _Float16* xfb = xfout + (size_t)b * NN * HH;
  _Float16* xTb2 = xTout + (size_t)b * HH * NN;
  #pragma unroll
  for (int nt = 0; nt < 4; ++nt) {
    const int col = wn * 64 + nt * 16 + fr;
    const float bv = bias[col];
    const int rowb = row0 + wm * 16 + fo * 4;
    f16x4 hc;
    #pragma unroll
    for (int m = 0; m < 4; ++m) {
      float v = fmaxf(fmaf(acc2[nt][m], 1024.0f, bv), 0.0f);
      hc[m] = (_Float16)v;
      xfb[(size_t)(rowb + m) * HH + col] = (_Float16)v;
    }
    *reinterpret_cast<f16x4*>(&xTb2[(size_t)col * NN + rowb]) = hc;
  }
}

// ----------------------------------------------------------- Sinkhorn ------
// Proven protocol (32 distributed flags w/ vote-in-flag early exit,
// agent-scope relaxed atomics, delta-trick accumulators) with LOGITS IN THE
// PROLOGUE (R10 code, exonerated by R11/R12 bisection — the failure was the
// gcn f16 overflow): each block builds its 16x512 tile of
// P0 = exp((10*tanh(x_i.x_j - 1e9*diag) + 0.01*gumbel)/3) via MFMA straight
// from xf (L2-resident). No rowmax needed: y in [-3.35,3.38] -> exp in
// [0.035,29.4]; r0 = 1/rowsum absorbs normalization. y never touches HBM.
// eps relaxed 1e-5 -> 1e-3: residual ~ 3.2*dm*maxP ~ 6.4e-6 << 4.09e-5.
__global__ __launch_bounds__(256) void sinkhorn_kernel(
    const _Float16* __restrict__ xf, const float* __restrict__ noise,
    float* __restrict__ cacc, unsigned int* __restrict__ flags,
    float* __restrict__ out)
{
  __shared__ float Pl[RB][513];
  __shared__ float cl[512];
  __shared__ float rl[RB];
  __shared__ float red[16][17];
  __shared__ float wmax[4];
  __shared__ int stopf;

  const int bid = blockIdx.x;
  const int b = bid >> 5, s = bid & 31;
  const int tid = threadIdx.x;
  const int i0 = s * RB;

  const _Float16* xb = xf + (size_t)b * NN * HH;
  const float* nzb = noise + ((size_t)b * NN + i0) * NN;
  const int wv = tid >> 6, lane = tid & 63;
  const int fr = lane & 15, fo = lane >> 4;
  const int jbase = wv * 128;

  // ---- fused logits -> P0 tile (16 rows x 512 cols) ----
  {
    float rowpart[4] = {0.f, 0.f, 0.f, 0.f};
    for (int jt = 0; jt < 8; ++jt) {
      const int jcol = jbase + jt * 16 + fr;
      f32x4 acc = {};
      #pragma unroll
      for (int ks = 0; ks < 4; ++ks) {
        f16x8 af = *reinterpret_cast<const f16x8*>(
            &xb[(size_t)(i0 + fr) * HH + ks * 32 + fo * 8]);
        f16x8 bf = *reinterpret_cast<const f16x8*>(
            &xb[(size_t)jcol * HH + ks * 32 + fo * 8]);
        acc = __builtin_amdgcn_mfma_f32_16x16x32_f16(af, bf, acc, 0, 0, 0);
      }
      #pragma unroll
      for (int m = 0; m < 4; ++m) {
        const int r = fo * 4 + m;
        float sv = acc[m];
        if (i0 + r == jcol) sv -= 1e9f;
        float th = 1.0f - 2.0f / (__expf(2.0f * sv) + 1.0f);   // tanh
        float u  = nzb[(size_t)r * NN + jcol];
        float eps = -__logf(-__logf(u));                        // Gumbel
        float e = __expf((10.0f * th + 0.01f * eps) * (1.0f / 3.0f));
        Pl[r][jcol] = e;
        rowpart[m] += e;
      }
    }
    #pragma unroll
    for (int m = 0; m < 4; ++m) {
      float v = rowpart[m];
      v += __shfl_xor(v, 1); v += __shfl_xor(v, 2);
      v += __shfl_xor(v, 4); v += __shfl_xor(v, 8);
      if (fr == 0) red[wv][fo * 4 + m] = v;
    }
  }
  cl[tid] = 1.0f; cl[tid + 256] = 1.0f;
  __syncthreads();
  if (tid < RB)
    rl[tid] = 1.0f / (red[0][tid] + red[1][tid] + red[2][tid] + red[3][tid]);
  __syncthreads();

  auto row_update = [&]() {
    const int i = tid & 15, ch = tid >> 4;
    const int j0 = ch * 32, st = (ch * 8) & 31;
    float p = 0.0f;
    #pragma unroll
    for (int q = 0; q < 32; ++q) {
      const int j = j0 + ((q + st) & 31);
      p = fmaf(Pl[i][j], cl[j], p);
    }
    red[ch][i] = p;
    __syncthreads();
    if (tid < RB) {
      float v = 0.0f;
      #pragma unroll
      for (int q = 0; q < 16; ++q) v += red[q][tid];
      rl[tid] = 1.0f / v;
    }
    __syncthreads();
  };

  unsigned int* myflag = flags + (size_t)(b * SB + s) * 64;
  float* ca0 = cacc + (size_t)b * 512;
  float* ca1 = cacc + (size_t)(BB + b) * 512;
  float pA0 = 0.f, pA1 = 0.f, pB0 = 0.f, pB1 = 0.f;
  unsigned int convbit = 0;

  for (int it = 0; it < 60; ++it) {
    float* ca  = (it & 1) ? ca1 : ca0;
    float& pv0 = (it & 1) ? pB0 : pA0;
    float& pv1 = (it & 1) ? pB1 : pA1;

    // phase A: partial column sums of diag(r)P0 over this slab -> atomicAdd
    float u0 = 0.0f, u1 = 0.0f;
    #pragma unroll
    for (int i2 = 0; i2 < RB; ++i2) {
      const float rv = rl[i2];
      u0 = fmaf(Pl[i2][tid],       rv, u0);
      u1 = fmaf(Pl[i2][tid + 256], rv, u1);
    }
    __hip_atomic_fetch_add(&ca[tid],       u0 - pv0, __ATOMIC_RELAXED, SCOPE_AGENT);
    __hip_atomic_fetch_add(&ca[tid + 256], u1 - pv1, __ATOMIC_RELAXED, SCOPE_AGENT);
    pv0 = u0; pv1 = u1;
    __syncthreads();  // vmcnt(0): this block's adds acked at coherence point

    // arrive: monotonic flag carries the convergence vote in bit 0
    if (tid == 0)
      __hip_atomic_store(myflag, ((unsigned int)(it + 1) << 1) | convbit,
                         __ATOMIC_RELAXED, SCOPE_AGENT);
    // wait (wave 0): 32 lanes poll the 32 flags; AND the votes via ballot
    if (tid < 64) {
      unsigned int v = 3u;              // lanes 32..63: arrived + vote yes
      if (tid < SB) {
        const unsigned int* fp = flags + (size_t)(b * SB + tid) * 64;
        do {
          v = __hip_atomic_load(fp, __ATOMIC_RELAXED, SCOPE_AGENT);
          if ((v >> 1) >= (unsigned int)(it + 1)) break;
          __builtin_amdgcn_s_sleep(1);
        } while (true);
      }
      unsigned long long m = __ballot((v & 1u) != 0u);
      if (tid == 0) stopf = ((m & 0xFFFFFFFFull) == 0xFFFFFFFFull) ? 1 : 0;
    }
    __syncthreads();
    if (stopf) break;   // unanimous: derived from the same 32 published words

    // phase B: read summed colsums; measure dm; update c; row pass
    float t0 = __hip_atomic_load(&ca[tid],       __ATOMIC_RELAXED, SCOPE_AGENT);
    float t1 = __hip_atomic_load(&ca[tid + 256], __ATOMIC_RELAXED, SCOPE_AGENT);
    float d = fmaxf(fabsf(fmaf(t0, cl[tid], -1.0f)),
                    fabsf(fmaf(t1, cl[tid + 256], -1.0f)));
    #pragma unroll
    for (int off = 32; off >= 1; off >>= 1) d = fmaxf(d, __shfl_xor(d, off));
    if ((tid & 63) == 0) wmax[tid >> 6] = d;
    cl[tid] = 1.0f / t0; cl[tid + 256] = 1.0f / t1;
    __syncthreads();
    const float dm = fmaxf(fmaxf(wmax[0], wmax[1]), fmaxf(wmax[2], wmax[3]));
    convbit = (dm < 1e-3f) ? 1u : 0u;
    row_update();
  }

  // final: out = r_i * P0_ij * c_j   (reads LDS only)
  float* Ob = out + ((size_t)b * NN + i0) * NN;
  #pragma unroll
  for (int i = 0; i < RB; ++i) {
    const float rv = rl[i];
    Ob[(size_t)i * NN + tid]       = rv * Pl[i][tid]       * cl[tid];
    Ob[(size_t)i * NN + tid + 256] = rv * Pl[i][tid + 256] * cl[tid + 256];
  }
}

// ------------------------------------------------------------- launch ------
extern "C" void kernel_launch(void* const* d_in, const int* in_sizes, int n_in,
                              void* d_out, int out_size, void* d_ws, size_t ws_size,
                              hipStream_t stream)
{
  const float* points = (const float*)d_in[0];
  const float* dist   = (const float*)d_in[1];
  const float* noise  = (const float*)d_in[2];
  const float* Wemb   = (const float*)d_in[3];
  const float* bemb   = (const float*)d_in[4];
  const float* W1 = (const float*)d_in[5]; const float* b1 = (const float*)d_in[6];
  const float* W2 = (const float*)d_in[7]; const float* b2 = (const float*)d_in[8];
  const float* W3 = (const float*)d_in[9]; const float* b3 = (const float*)d_in[10];
  float* out = (float*)d_out;

  char* ws = (char*)d_ws;                              // ws_size = 256 MiB
  _Float16* xfA = (_Float16*)ws;                       // 2 MB
  _Float16* xTA = (_Float16*)(ws + (2u << 20));        // 2 MB
  _Float16* xfB = (_Float16*)(ws + (4u << 20));        // 2 MB
  _Float16* xTB = (_Float16*)(ws + (6u << 20));        // 2 MB
  char* ctrl = ws + (8u << 20);
  float*        cacc  = (float*)ctrl;                  // 64 KB
  unsigned int* flags = (unsigned int*)(ctrl + (64u << 10));  // 128 KB

  // 3 fused GCN layers (layer 1 embeds on the fly + zeroes ctrl)
  gcn_kernel<true><<<256, 256, 0, stream>>>(dist, nullptr, points, Wemb, bemb,
                                            W1, b1, xfA, xTA, (unsigned int*)ctrl);
  gcn_kernel<false><<<256, 256, 0, stream>>>(dist, xTA, nullptr, nullptr, nullptr,
                                             W2, b2, xfB, xTB, nullptr);
  gcn_kernel<false><<<256, 256, 0, stream>>>(dist, xTB, nullptr, nullptr, nullptr,
                                             W3, b3, xfA, xTA, nullptr);

  // Sinkhorn (logits fused in prologue; proven barrier protocol; eps=1e-3)
  const _Float16* xfc = xfA; const float* nzc = noise;
  float* caccP = cacc; unsigned int* flagsP = flags; float* outP = out;
  void* args[] = {(void*)&xfc, (void*)&nzc, (void*)&caccP, (void*)&flagsP, (void*)&outP};
  hipLaunchCooperativeKernel(reinterpret_cast<void*>(sinkhorn_kernel),
                             dim3(BB * SB), dim3(256), args, 0, stream);
}

// Round 15
// 85.624 us; speedup vs baseline: 4.3830x; 1.1234x over previous
//
#include <hip/hip_runtime.h>

// Problem constants
#define BB 16
#define NN 512
#define HH 128
#define SB 32   // sinkhorn slabs (blocks) per batch
#define RB 16   // sinkhorn rows per slab

#define SCOPE_AGENT __HIP_MEMORY_SCOPE_AGENT

typedef _Float16 f16x8 __attribute__((ext_vector_type(8)));
typedef _Float16 f16x4 __attribute__((ext_vector_type(4)));
typedef float    f32x4 __attribute__((ext_vector_type(4)));

// ------------------------------------------------------------ fused GCN ----
// R13-proven math (Cl parked *2^-10 against f16 overflow) with two structural
// upgrades: (1) ping-pong LDS staging -> ONE barrier per K-step (was 2) and
// global loads overlap MFMA; (2) layer 1 (EMB) stores the f16 adjacency it
// already computes to adjws; layers 2/3 load it (half the bytes, no exp).
template <bool EMB>
__global__ __launch_bounds__(256) void gcn_kernel(
    const float* __restrict__ dist, _Float16* __restrict__ adjws,
    const _Float16* __restrict__ xTin,
    const float* __restrict__ pts, const float* __restrict__ Wemb,
    const float* __restrict__ bemb,
    const float* __restrict__ W, const float* __restrict__ bias,
    _Float16* __restrict__ xfout, _Float16* __restrict__ xTout,
    unsigned int* __restrict__ ctrlz)
{
  __shared__ _Float16 Al2[2][32][40];   // adj tile (f16), bank-spread
  __shared__ _Float16 Bl2[2][128][40];  // x^T tile
  __shared__ _Float16 Cl[32][136];      // nb tile * 2^-10 (phase-1 result)
  __shared__ _Float16 Wl[128][136];     // W transposed: Wl[n][k] = W[k][n]

  const int bid = blockIdx.x;
  const int mt = bid & 15, b = bid >> 4;
  const int tid = threadIdx.x;
  const int row0 = mt * 32;

  if (EMB) {  // fold ctrl zeroing into layer 1 (stream-ordered)
    int idx = bid * 256 + tid;
    if (idx < 49152) ctrlz[idx] = 0u;
  }

  // stage W transposed (128x128 = 16384 elems / 256 thr = 64 reps)
  #pragma unroll
  for (int rep = 0; rep < 64; ++rep) {
    const int idx = rep * 256 + tid;
    const int k = idx >> 7, n = idx & 127;
    Wl[n][k] = (_Float16)W[(size_t)k * HH + n];
  }

  const float* Ab = dist + ((size_t)b * NN + row0) * NN;
  _Float16* adjwb = adjws + ((size_t)b * NN + row0) * NN;         // layer 1 out
  const _Float16* adjrb = adjws + ((size_t)b * NN + row0) * NN;   // layers 2/3 in
  const _Float16* xTb = EMB ? nullptr : (xTin + (size_t)b * HH * NN);

  const int wv = tid >> 6, lane = tid & 63;
  const int wm = wv >> 1, wn = wv & 1;
  const int fr = lane & 15, fo = lane >> 4;

  // EMB: hoist per-h weights (thread handles h-rows n0 and n0+64)
  float we0a = 0.f, we1a = 0.f, ba = 0.f, we0b = 0.f, we1b = 0.f, bb2 = 0.f;
  const int n0 = tid >> 2, q4 = tid & 3;
  if (EMB) {
    we0a = Wemb[n0];      we1a = Wemb[HH + n0];      ba  = bemb[n0];
    we0b = Wemb[n0 + 64]; we1b = Wemb[HH + n0 + 64]; bb2 = bemb[n0 + 64];
  }

  // ---- staging lambdas (write into buffer `buf` for K-chunk k0) ----
  auto stageA = [&](int buf, int k0) {
    if (EMB) {  // f32 dist -> exp(-x) -> f16 (+ store adj16 for layers 2/3)
      const int r = tid >> 3, q = tid & 7;
      float4 v = *reinterpret_cast<const float4*>(&Ab[(size_t)r * NN + k0 + q * 4]);
      f16x4 h;
      h[0] = (_Float16)__expf(-v.x); h[1] = (_Float16)__expf(-v.y);
      h[2] = (_Float16)__expf(-v.z); h[3] = (_Float16)__expf(-v.w);
      *reinterpret_cast<f16x4*>(&Al2[buf][r][q * 4]) = h;
      *reinterpret_cast<f16x4*>(&adjwb[(size_t)r * NN + k0 + q * 4]) = h;
    } else {    // direct f16 adjacency load
      const int r = tid >> 3, q = tid & 7;
      *reinterpret_cast<f16x4*>(&Al2[buf][r][q * 4]) =
          *reinterpret_cast<const f16x4*>(&adjrb[(size_t)r * NN + k0 + q * 4]);
    }
  };
  auto stageB = [&](int buf, int k0) {
    if (!EMB) {  // from xT rows (contig k)
      #pragma unroll
      for (int it = 0; it < 2; ++it) {
        const int slot = it * 256 + tid;
        const int n = slot >> 2, q = slot & 3;
        f16x8 v = *reinterpret_cast<const f16x8*>(&xTb[(size_t)n * NN + k0 + q * 8]);
        *reinterpret_cast<f16x8*>(&Bl2[buf][n][q * 8]) = v;
      }
    } else {     // x0^T computed on the fly
      float2 pv[8];
      #pragma unroll
      for (int e = 0; e < 8; ++e)
        pv[e] = *reinterpret_cast<const float2*>(
            &pts[((size_t)b * NN + k0 + q4 * 8 + e) * 2]);
      f16x8 va, vb;
      #pragma unroll
      for (int e = 0; e < 8; ++e) {
        va[e] = (_Float16)fmaf(pv[e].x, we0a, fmaf(pv[e].y, we1a, ba));
        vb[e] = (_Float16)fmaf(pv[e].x, we0b, fmaf(pv[e].y, we1b, bb2));
      }
      *reinterpret_cast<f16x8*>(&Bl2[buf][n0][q4 * 8]) = va;
      *reinterpret_cast<f16x8*>(&Bl2[buf][n0 + 64][q4 * 8]) = vb;
    }
  };

  f32x4 acc[4] = {};

  stageA(0, 0);
  stageB(0, 0);
  __syncthreads();

  for (int k0 = 0; k0 < NN; k0 += 32) {
    const int cur = (k0 >> 5) & 1;
    if (k0 + 32 < NN) {        // stage next chunk into the other buffer
      stageA(cur ^ 1, k0 + 32);
      stageB(cur ^ 1, k0 + 32);
    }
    f16x8 af = *reinterpret_cast<const f16x8*>(&Al2[cur][wm * 16 + fr][fo * 8]);
    #pragma unroll
    for (int nt = 0; nt < 4; ++nt) {
      f16x8 bf = *reinterpret_cast<const f16x8*>(&Bl2[cur][wn * 64 + nt * 16 + fr][fo * 8]);
      acc[nt] = __builtin_amdgcn_mfma_f32_16x16x32_f16(af, bf, acc[nt], 0, 0, 0);
    }
    __syncthreads();  // next-stage writes landed; everyone done reading cur
  }

  // park nb tile in LDS, scaled 2^-10 (exact) to stay inside f16 range
  #pragma unroll
  for (int nt = 0; nt < 4; ++nt) {
    const int col = wn * 64 + nt * 16 + fr;
    #pragma unroll
    for (int m = 0; m < 4; ++m)
      Cl[wm * 16 + fo * 4 + m][col] = (_Float16)(acc[nt][m] * 0x1p-10f);
  }
  __syncthreads();

  // phase 2: out = relu((nb_scaled @ W) * 2^10 + bias)
  f32x4 acc2[4] = {};
  #pragma unroll
  for (int ks = 0; ks < 4; ++ks) {
    f16x8 af2 = *reinterpret_cast<const f16x8*>(&Cl[wm * 16 + fr][ks * 32 + fo * 8]);
    #pragma unroll
    for (int nt = 0; nt < 4; ++nt) {
      f16x8 bf2 = *reinterpret_cast<const f16x8*>(&Wl[wn * 64 + nt * 16 + fr][ks * 32 + fo * 8]);
      acc2[nt] = __builtin_amdgcn_mfma_f32_16x16x32_f16(af2, bf2, acc2[nt], 0, 0, 0);
    }
  }

  _Float16* xfb = xfout + (size_t)b * NN * HH;
  _Float16* xTb2 = xTout + (size_t)b * HH * NN;
  #pragma unroll
  for (int nt = 0; nt < 4; ++nt) {
    const int col = wn * 64 + nt * 16 + fr;
    const float bv = bias[col];
    const int rowb = row0 + wm * 16 + fo * 4;
    f16x4 hc;
    #pragma unroll
    for (int m = 0; m < 4; ++m) {
      float v = fmaxf(fmaf(acc2[nt][m], 1024.0f, bv), 0.0f);
      hc[m] = (_Float16)v;
      xfb[(size_t)(rowb + m) * HH + col] = (_Float16)v;
    }
    *reinterpret_cast<f16x4*>(&xTb2[(size_t)col * NN + rowb]) = hc;
  }
}

// ----------------------------------------------------------- Sinkhorn ------
// R14-PROVEN protocol and prologue, unchanged except: A-fragments hoisted out
// of the jt loop (loop-invariant) and the final out write vectorized float4.
__global__ __launch_bounds__(256) void sinkhorn_kernel(
    const _Float16* __restrict__ xf, const float* __restrict__ noise,
    float* __restrict__ cacc, unsigned int* __restrict__ flags,
    float* __restrict__ out)
{
  __shared__ float Pl[RB][513];
  __shared__ float cl[512];
  __shared__ float rl[RB];
  __shared__ float red[16][17];
  __shared__ float wmax[4];
  __shared__ int stopf;

  const int bid = blockIdx.x;
  const int b = bid >> 5, s = bid & 31;
  const int tid = threadIdx.x;
  const int i0 = s * RB;

  const _Float16* xb = xf + (size_t)b * NN * HH;
  const float* nzb = noise + ((size_t)b * NN + i0) * NN;
  const int wv = tid >> 6, lane = tid & 63;
  const int fr = lane & 15, fo = lane >> 4;
  const int jbase = wv * 128;

  // ---- fused logits -> P0 tile (16 rows x 512 cols) ----
  {
    f16x8 af[4];
    #pragma unroll
    for (int ks = 0; ks < 4; ++ks)
      af[ks] = *reinterpret_cast<const f16x8*>(
          &xb[(size_t)(i0 + fr) * HH + ks * 32 + fo * 8]);

    float rowpart[4] = {0.f, 0.f, 0.f, 0.f};
    for (int jt = 0; jt < 8; ++jt) {
      const int jcol = jbase + jt * 16 + fr;
      f32x4 acc = {};
      #pragma unroll
      for (int ks = 0; ks < 4; ++ks) {
        f16x8 bf = *reinterpret_cast<const f16x8*>(
            &xb[(size_t)jcol * HH + ks * 32 + fo * 8]);
        acc = __builtin_amdgcn_mfma_f32_16x16x32_f16(af[ks], bf, acc, 0, 0, 0);
      }
      #pragma unroll
      for (int m = 0; m < 4; ++m) {
        const int r = fo * 4 + m;
        float sv = acc[m];
        if (i0 + r == jcol) sv -= 1e9f;
        float th = 1.0f - 2.0f / (__expf(2.0f * sv) + 1.0f);   // tanh
        float u  = nzb[(size_t)r * NN + jcol];
        float eps = -__logf(-__logf(u));                        // Gumbel
        float e = __expf((10.0f * th + 0.01f * eps) * (1.0f / 3.0f));
        Pl[r][jcol] = e;
        rowpart[m] += e;
      }
    }
    #pragma unroll
    for (int m = 0; m < 4; ++m) {
      float v = rowpart[m];
      v += __shfl_xor(v, 1); v += __shfl_xor(v, 2);
      v += __shfl_xor(v, 4); v += __shfl_xor(v, 8);
      if (fr == 0) red[wv][fo * 4 + m] = v;
    }
  }
  cl[tid] = 1.0f; cl[tid + 256] = 1.0f;
  __syncthreads();
  if (tid < RB)
    rl[tid] = 1.0f / (red[0][tid] + red[1][tid] + red[2][tid] + red[3][tid]);
  __syncthreads();

  auto row_update = [&]() {
    const int i = tid & 15, ch = tid >> 4;
    const int j0 = ch * 32, st = (ch * 8) & 31;
    float p = 0.0f;
    #pragma unroll
    for (int q = 0; q < 32; ++q) {
      const int j = j0 + ((q + st) & 31);
      p = fmaf(Pl[i][j], cl[j], p);
    }
    red[ch][i] = p;
    __syncthreads();
    if (tid < RB) {
      float v = 0.0f;
      #pragma unroll
      for (int q = 0; q < 16; ++q) v += red[q][tid];
      rl[tid] = 1.0f / v;
    }
    __syncthreads();
  };

  unsigned int* myflag = flags + (size_t)(b * SB + s) * 64;
  float* ca0 = cacc + (size_t)b * 512;
  float* ca1 = cacc + (size_t)(BB + b) * 512;
  float pA0 = 0.f, pA1 = 0.f, pB0 = 0.f, pB1 = 0.f;
  unsigned int convbit = 0;

  for (int it = 0; it < 60; ++it) {
    float* ca  = (it & 1) ? ca1 : ca0;
    float& pv0 = (it & 1) ? pB0 : pA0;
    float& pv1 = (it & 1) ? pB1 : pA1;

    // phase A: partial column sums of diag(r)P0 over this slab -> atomicAdd
    float u0 = 0.0f, u1 = 0.0f;
    #pragma unroll
    for (int i2 = 0; i2 < RB; ++i2) {
      const float rv = rl[i2];
      u0 = fmaf(Pl[i2][tid],       rv, u0);
      u1 = fmaf(Pl[i2][tid + 256], rv, u1);
    }
    __hip_atomic_fetch_add(&ca[tid],       u0 - pv0, __ATOMIC_RELAXED, SCOPE_AGENT);
    __hip_atomic_fetch_add(&ca[tid + 256], u1 - pv1, __ATOMIC_RELAXED, SCOPE_AGENT);
    pv0 = u0; pv1 = u1;
    __syncthreads();  // vmcnt(0): this block's adds acked at coherence point

    // arrive: monotonic flag carries the convergence vote in bit 0
    if (tid == 0)
      __hip_atomic_store(myflag, ((unsigned int)(it + 1) << 1) | convbit,
                         __ATOMIC_RELAXED, SCOPE_AGENT);
    // wait (wave 0): 32 lanes poll the 32 flags; AND the votes via ballot
    if (tid < 64) {
      unsigned int v = 3u;              // lanes 32..63: arrived + vote yes
      if (tid < SB) {
        const unsigned int* fp = flags + (size_t)(b * SB + tid) * 64;
        do {
          v = __hip_atomic_load(fp, __ATOMIC_RELAXED, SCOPE_AGENT);
          if ((v >> 1) >= (unsigned int)(it + 1)) break;
          __builtin_amdgcn_s_sleep(1);
        } while (true);
      }
      unsigned long long m = __ballot((v & 1u) != 0u);
      if (tid == 0) stopf = ((m & 0xFFFFFFFFull) == 0xFFFFFFFFull) ? 1 : 0;
    }
    __syncthreads();
    if (stopf) break;   // unanimous: derived from the same 32 published words

    // phase B: read summed colsums; measure dm; update c; row pass
    float t0 = __hip_atomic_load(&ca[tid],       __ATOMIC_RELAXED, SCOPE_AGENT);
    float t1 = __hip_atomic_load(&ca[tid + 256], __ATOMIC_RELAXED, SCOPE_AGENT);
    float d = fmaxf(fabsf(fmaf(t0, cl[tid], -1.0f)),
                    fabsf(fmaf(t1, cl[tid + 256], -1.0f)));
    #pragma unroll
    for (int off = 32; off >= 1; off >>= 1) d = fmaxf(d, __shfl_xor(d, off));
    if ((tid & 63) == 0) wmax[tid >> 6] = d;
    cl[tid] = 1.0f / t0; cl[tid + 256] = 1.0f / t1;
    __syncthreads();
    const float dm = fmaxf(fmaxf(wmax[0], wmax[1]), fmaxf(wmax[2], wmax[3]));
    convbit = (dm < 1e-3f) ? 1u : 0u;
    row_update();
  }

  // final: out = r_i * P0_ij * c_j   (float4, reads LDS only)
  float* Ob = out + ((size_t)b * NN + i0) * NN;
  #pragma unroll
  for (int rep = 0; rep < 8; ++rep) {
    const int row = rep * 2 + (tid >> 7);     // 0..15
    const int c4  = (tid & 127) * 4;          // 0..508
    const float rv = rl[row];
    float4 o;
    o.x = rv * Pl[row][c4 + 0] * cl[c4 + 0];
    o.y = rv * Pl[row][c4 + 1] * cl[c4 + 1];
    o.z = rv * Pl[row][c4 + 2] * cl[c4 + 2];
    o.w = rv * Pl[row][c4 + 3] * cl[c4 + 3];
    *reinterpret_cast<float4*>(&Ob[(size_t)row * NN + c4]) = o;
  }
}

// ------------------------------------------------------------- launch ------
extern "C" void kernel_launch(void* const* d_in, const int* in_sizes, int n_in,
                              void* d_out, int out_size, void* d_ws, size_t ws_size,
                              hipStream_t stream)
{
  const float* points = (const float*)d_in[0];
  const float* dist   = (const float*)d_in[1];
  const float* noise  = (const float*)d_in[2];
  const float* Wemb   = (const float*)d_in[3];
  const float* bemb   = (const float*)d_in[4];
  const float* W1 = (const float*)d_in[5]; const float* b1 = (const float*)d_in[6];
  const float* W2 = (const float*)d_in[7]; const float* b2 = (const float*)d_in[8];
  const float* W3 = (const float*)d_in[9]; const float* b3 = (const float*)d_in[10];
  float* out = (float*)d_out;

  char* ws = (char*)d_ws;                              // ws_size = 256 MiB
  _Float16* xfA = (_Float16*)ws;                       // 2 MB
  _Float16* xTA = (_Float16*)(ws + (2u << 20));        // 2 MB
  _Float16* xfB = (_Float16*)(ws + (4u << 20));        // 2 MB
  _Float16* xTB = (_Float16*)(ws + (6u << 20));        // 2 MB
  _Float16* adjw = (_Float16*)(ws + (8u << 20));       // 8 MB (f16 adjacency)
  char* ctrl = ws + (16u << 20);
  float*        cacc  = (float*)ctrl;                  // 64 KB
  unsigned int* flags = (unsigned int*)(ctrl + (64u << 10));  // 128 KB
  // ws usage: 16 MB + 192 KB << 256 MiB  ✓

  // 3 fused GCN layers (layer 1 embeds on the fly, writes adj16, zeroes ctrl)
  gcn_kernel<true><<<256, 256, 0, stream>>>(dist, adjw, nullptr, points, Wemb, bemb,
                                            W1, b1, xfA, xTA, (unsigned int*)ctrl);
  gcn_kernel<false><<<256, 256, 0, stream>>>(nullptr, adjw, xTA, nullptr, nullptr, nullptr,
                                             W2, b2, xfB, xTB, nullptr);
  gcn_kernel<false><<<256, 256, 0, stream>>>(nullptr, adjw, xTB, nullptr, nullptr, nullptr,
                                             W3, b3, xfA, xTA, nullptr);

  // Sinkhorn (logits fused in prologue; proven barrier protocol; eps=1e-3)
  const _Float16* xfc = xfA; const float* nzc = noise;
  float* caccP = cacc; unsigned int* flagsP = flags; float* outP = out;
  void* args[] = {(void*)&xfc, (void*)&nzc, (void*)&caccP, (void*)&flagsP, (void*)&outP};
  hipLaunchCooperativeKernel(reinterpret_cast<void*>(sinkhorn_kernel),
                             dim3(BB * SB), dim3(256), args, 0, stream);
}

// Round 16
// 84.756 us; speedup vs baseline: 4.4279x; 1.0102x over previous
//
#include <hip/hip_runtime.h>

// Problem constants
#define BB 16
#define NN 512
#define HH 128
#define SB 32   // sinkhorn slabs (blocks) per batch
#define RB 16   // sinkhorn rows per slab

#define SCOPE_AGENT __HIP_MEMORY_SCOPE_AGENT

typedef _Float16 f16x8 __attribute__((ext_vector_type(8)));
typedef _Float16 f16x4 __attribute__((ext_vector_type(4)));
typedef _Float16 f16x2 __attribute__((ext_vector_type(2)));
typedef float    f32x4 __attribute__((ext_vector_type(4)));

// ------------------------------------------------------------ fused GCN ----
// R15-proven math (ping-pong staging, 1 barrier/K-step; Cl parked *2^-10
// against f16 overflow; layer 1 writes f16 adjacency for layers 2/3), now at
// 16-row tiles x 512 blocks = 2 blocks/CU (was 32-row x 256 = 1/CU) so one
// block's staging overlaps the other's MFMA. Per wave: 32 output cols.
template <bool EMB>
__global__ __launch_bounds__(256) void gcn_kernel(
    const float* __restrict__ dist, _Float16* __restrict__ adjws,
    const _Float16* __restrict__ xTin,
    const float* __restrict__ pts, const float* __restrict__ Wemb,
    const float* __restrict__ bemb,
    const float* __restrict__ W, const float* __restrict__ bias,
    _Float16* __restrict__ xfout, _Float16* __restrict__ xTout,
    unsigned int* __restrict__ ctrlz)
{
  __shared__ _Float16 Al2[2][16][40];   // adj tile (f16), bank-spread
  __shared__ _Float16 Bl2[2][128][40];  // x^T tile
  __shared__ _Float16 Cl[16][136];      // nb tile * 2^-10 (phase-1 result)
  __shared__ _Float16 Wl[128][136];     // W transposed: Wl[n][k] = W[k][n]

  const int bid = blockIdx.x;
  const int mt = bid & 31, b = bid >> 5;
  const int tid = threadIdx.x;
  const int row0 = mt * 16;

  if (EMB) {  // fold ctrl zeroing into layer 1 (stream-ordered)
    int idx = bid * 256 + tid;
    if (idx < 49152) ctrlz[idx] = 0u;
  }

  // stage W transposed (128x128 = 16384 elems / 256 thr = 64 reps)
  #pragma unroll
  for (int rep = 0; rep < 64; ++rep) {
    const int idx = rep * 256 + tid;
    const int k = idx >> 7, n = idx & 127;
    Wl[n][k] = (_Float16)W[(size_t)k * HH + n];
  }

  const float* Ab = dist + ((size_t)b * NN + row0) * NN;
  _Float16* adjwb = adjws + ((size_t)b * NN + row0) * NN;         // layer 1 out
  const _Float16* adjrb = adjws + ((size_t)b * NN + row0) * NN;   // layers 2/3 in
  const _Float16* xTb = EMB ? nullptr : (xTin + (size_t)b * HH * NN);

  const int wv = tid >> 6, lane = tid & 63;
  const int fr = lane & 15, fo = lane >> 4;

  // EMB: hoist per-h weights (thread handles h-rows n0 and n0+64)
  float we0a = 0.f, we1a = 0.f, ba = 0.f, we0b = 0.f, we1b = 0.f, bb2 = 0.f;
  const int n0 = tid >> 2, q4 = tid & 3;
  if (EMB) {
    we0a = Wemb[n0];      we1a = Wemb[HH + n0];      ba  = bemb[n0];
    we0b = Wemb[n0 + 64]; we1b = Wemb[HH + n0 + 64]; bb2 = bemb[n0 + 64];
  }

  // ---- staging lambdas (write into buffer `buf` for K-chunk k0) ----
  auto stageA = [&](int buf, int k0) {
    const int r = tid >> 4, q = tid & 15;   // 16 rows x 16 pairs = 512 f16
    if (EMB) {  // f32 dist -> exp(-x) -> f16 (+ store adj16 for layers 2/3)
      float2 v = *reinterpret_cast<const float2*>(&Ab[(size_t)r * NN + k0 + q * 2]);
      f16x2 h;
      h[0] = (_Float16)__expf(-v.x); h[1] = (_Float16)__expf(-v.y);
      *reinterpret_cast<f16x2*>(&Al2[buf][r][q * 2]) = h;
      *reinterpret_cast<f16x2*>(&adjwb[(size_t)r * NN + k0 + q * 2]) = h;
    } else {    // direct f16 adjacency load
      *reinterpret_cast<f16x2*>(&Al2[buf][r][q * 2]) =
          *reinterpret_cast<const f16x2*>(&adjrb[(size_t)r * NN + k0 + q * 2]);
    }
  };
  auto stageB = [&](int buf, int k0) {
    if (!EMB) {  // from xT rows (contig k)
      #pragma unroll
      for (int it = 0; it < 2; ++it) {
        const int slot = it * 256 + tid;
        const int n = slot >> 2, q = slot & 3;
        f16x8 v = *reinterpret_cast<const f16x8*>(&xTb[(size_t)n * NN + k0 + q * 8]);
        *reinterpret_cast<f16x8*>(&Bl2[buf][n][q * 8]) = v;
      }
    } else {     // x0^T computed on the fly
      float2 pv[8];
      #pragma unroll
      for (int e = 0; e < 8; ++e)
        pv[e] = *reinterpret_cast<const float2*>(
            &pts[((size_t)b * NN + k0 + q4 * 8 + e) * 2]);
      f16x8 va, vb;
      #pragma unroll
      for (int e = 0; e < 8; ++e) {
        va[e] = (_Float16)fmaf(pv[e].x, we0a, fmaf(pv[e].y, we1a, ba));
        vb[e] = (_Float16)fmaf(pv[e].x, we0b, fmaf(pv[e].y, we1b, bb2));
      }
      *reinterpret_cast<f16x8*>(&Bl2[buf][n0][q4 * 8]) = va;
      *reinterpret_cast<f16x8*>(&Bl2[buf][n0 + 64][q4 * 8]) = vb;
    }
  };

  f32x4 acc[2] = {};

  stageA(0, 0);
  stageB(0, 0);
  __syncthreads();

  for (int k0 = 0; k0 < NN; k0 += 32) {
    const int cur = (k0 >> 5) & 1;
    if (k0 + 32 < NN) {        // stage next chunk into the other buffer
      stageA(cur ^ 1, k0 + 32);
      stageB(cur ^ 1, k0 + 32);
    }
    f16x8 af = *reinterpret_cast<const f16x8*>(&Al2[cur][fr][fo * 8]);
    #pragma unroll
    for (int nt = 0; nt < 2; ++nt) {
      f16x8 bf = *reinterpret_cast<const f16x8*>(&Bl2[cur][wv * 32 + nt * 16 + fr][fo * 8]);
      acc[nt] = __builtin_amdgcn_mfma_f32_16x16x32_f16(af, bf, acc[nt], 0, 0, 0);
    }
    __syncthreads();  // next-stage writes landed; everyone done reading cur
  }

  // park nb tile in LDS, scaled 2^-10 (exact) to stay inside f16 range
  #pragma unroll
  for (int nt = 0; nt < 2; ++nt) {
    const int col = wv * 32 + nt * 16 + fr;
    #pragma unroll
    for (int m = 0; m < 4; ++m)
      Cl[fo * 4 + m][col] = (_Float16)(acc[nt][m] * 0x1p-10f);
  }
  __syncthreads();

  // phase 2: out = relu((nb_scaled @ W) * 2^10 + bias)
  f32x4 acc2[2] = {};
  #pragma unroll
  for (int ks = 0; ks < 4; ++ks) {
    f16x8 af2 = *reinterpret_cast<const f16x8*>(&Cl[fr][ks * 32 + fo * 8]);
    #pragma unroll
    for (int nt = 0; nt < 2; ++nt) {
      f16x8 bf2 = *reinterpret_cast<const f16x8*>(&Wl[wv * 32 + nt * 16 + fr][ks * 32 + fo * 8]);
      acc2[nt] = __builtin_amdgcn_mfma_f32_16x16x32_f16(af2, bf2, acc2[nt], 0, 0, 0);
    }
  }

  _Float16* xfb = xfout + (size_t)b * NN * HH;
  _Float16* xTb2 = xTout + (size_t)b * HH * NN;
  #pragma unroll
  for (int nt = 0; nt < 2; ++nt) {
    const int col = wv * 32 + nt * 16 + fr;
    const float bv = bias[col];
    const int rowb = row0 + fo * 4;
    f16x4 hc;
    #pragma unroll
    for (int m = 0; m < 4; ++m) {
      float v = fmaxf(fmaf(acc2[nt][m], 1024.0f, bv), 0.0f);
      hc[m] = (_Float16)v;
      xfb[(size_t)(rowb + m) * HH + col] = (_Float16)v;
    }
    *reinterpret_cast<f16x4*>(&xTb2[(size_t)col * NN + rowb]) = hc;
  }
}

// ----------------------------------------------------------- Sinkhorn ------
// R15-PROVEN protocol and prologue, unchanged except eps 1e-3 -> 2e-3
// (residual ~ 3.2*dm*maxP ~ 1.3e-5; stacked with 1.5e-5 bf16 floor = 2.8e-5
// < 4.09e-5 threshold).
__global__ __launch_bounds__(256) void sinkhorn_kernel(
    const _Float16* __restrict__ xf, const float* __restrict__ noise,
    float* __restrict__ cacc, unsigned int* __restrict__ flags,
    float* __restrict__ out)
{
  __shared__ float Pl[RB][513];
  __shared__ float cl[512];
  __shared__ float rl[RB];
  __shared__ float red[16][17];
  __shared__ float wmax[4];
  __shared__ int stopf;

  const int bid = blockIdx.x;
  const int b = bid >> 5, s = bid & 31;
  const int tid = threadIdx.x;
  const int i0 = s * RB;

  const _Float16* xb = xf + (size_t)b * NN * HH;
  const float* nzb = noise + ((size_t)b * NN + i0) * NN;
  const int wv = tid >> 6, lane = tid & 63;
  const int fr = lane & 15, fo = lane >> 4;
  const int jbase = wv * 128;

  // ---- fused logits -> P0 tile (16 rows x 512 cols) ----
  {
    f16x8 af[4];
    #pragma unroll
    for (int ks = 0; ks < 4; ++ks)
      af[ks] = *reinterpret_cast<const f16x8*>(
          &xb[(size_t)(i0 + fr) * HH + ks * 32 + fo * 8]);

    float rowpart[4] = {0.f, 0.f, 0.f, 0.f};
    for (int jt = 0; jt < 8; ++jt) {
      const int jcol = jbase + jt * 16 + fr;
      f32x4 acc = {};
      #pragma unroll
      for (int ks = 0; ks < 4; ++ks) {
        f16x8 bf = *reinterpret_cast<const f16x8*>(
            &xb[(size_t)jcol * HH + ks * 32 + fo * 8]);
        acc = __builtin_amdgcn_mfma_f32_16x16x32_f16(af[ks], bf, acc, 0, 0, 0);
      }
      #pragma unroll
      for (int m = 0; m < 4; ++m) {
        const int r = fo * 4 + m;
        float sv = acc[m];
        if (i0 + r == jcol) sv -= 1e9f;
        float th = 1.0f - 2.0f / (__expf(2.0f * sv) + 1.0f);   // tanh
        float u  = nzb[(size_t)r * NN + jcol];
        float eps = -__logf(-__logf(u));                        // Gumbel
        float e = __expf((10.0f * th + 0.01f * eps) * (1.0f / 3.0f));
        Pl[r][jcol] = e;
        rowpart[m] += e;
      }
    }
    #pragma unroll
    for (int m = 0; m < 4; ++m) {
      float v = rowpart[m];
      v += __shfl_xor(v, 1); v += __shfl_xor(v, 2);
      v += __shfl_xor(v, 4); v += __shfl_xor(v, 8);
      if (fr == 0) red[wv][fo * 4 + m] = v;
    }
  }
  cl[tid] = 1.0f; cl[tid + 256] = 1.0f;
  __syncthreads();
  if (tid < RB)
    rl[tid] = 1.0f / (red[0][tid] + red[1][tid] + red[2][tid] + red[3][tid]);
  __syncthreads();

  auto row_update = [&]() {
    const int i = tid & 15, ch = tid >> 4;
    const int j0 = ch * 32, st = (ch * 8) & 31;
    float p = 0.0f;
    #pragma unroll
    for (int q = 0; q < 32; ++q) {
      const int j = j0 + ((q + st) & 31);
      p = fmaf(Pl[i][j], cl[j], p);
    }
    red[ch][i] = p;
    __syncthreads();
    if (tid < RB) {
      float v = 0.0f;
      #pragma unroll
      for (int q = 0; q < 16; ++q) v += red[q][tid];
      rl[tid] = 1.0f / v;
    }
    __syncthreads();
  };

  unsigned int* myflag = flags + (size_t)(b * SB + s) * 64;
  float* ca0 = cacc + (size_t)b * 512;
  float* ca1 = cacc + (size_t)(BB + b) * 512;
  float pA0 = 0.f, pA1 = 0.f, pB0 = 0.f, pB1 = 0.f;
  unsigned int convbit = 0;

  for (int it = 0; it < 60; ++it) {
    float* ca  = (it & 1) ? ca1 : ca0;
    float& pv0 = (it & 1) ? pB0 : pA0;
    float& pv1 = (it & 1) ? pB1 : pA1;

    // phase A: partial column sums of diag(r)P0 over this slab -> atomicAdd
    float u0 = 0.0f, u1 = 0.0f;
    #pragma unroll
    for (int i2 = 0; i2 < RB; ++i2) {
      const float rv = rl[i2];
      u0 = fmaf(Pl[i2][tid],       rv, u0);
      u1 = fmaf(Pl[i2][tid + 256], rv, u1);
    }
    __hip_atomic_fetch_add(&ca[tid],       u0 - pv0, __ATOMIC_RELAXED, SCOPE_AGENT);
    __hip_atomic_fetch_add(&ca[tid + 256], u1 - pv1, __ATOMIC_RELAXED, SCOPE_AGENT);
    pv0 = u0; pv1 = u1;
    __syncthreads();  // vmcnt(0): this block's adds acked at coherence point

    // arrive: monotonic flag carries the convergence vote in bit 0
    if (tid == 0)
      __hip_atomic_store(myflag, ((unsigned int)(it + 1) << 1) | convbit,
                         __ATOMIC_RELAXED, SCOPE_AGENT);
    // wait (wave 0): 32 lanes poll the 32 flags; AND the votes via ballot
    if (tid < 64) {
      unsigned int v = 3u;              // lanes 32..63: arrived + vote yes
      if (tid < SB) {
        const unsigned int* fp = flags + (size_t)(b * SB + tid) * 64;
        do {
          v = __hip_atomic_load(fp, __ATOMIC_RELAXED, SCOPE_AGENT);
          if ((v >> 1) >= (unsigned int)(it + 1)) break;
          __builtin_amdgcn_s_sleep(1);
        } while (true);
      }
      unsigned long long m = __ballot((v & 1u) != 0u);
      if (tid == 0) stopf = ((m & 0xFFFFFFFFull) == 0xFFFFFFFFull) ? 1 : 0;
    }
    __syncthreads();
    if (stopf) break;   // unanimous: derived from the same 32 published words

    // phase B: read summed colsums; measure dm; update c; row pass
    float t0 = __hip_atomic_load(&ca[tid],       __ATOMIC_RELAXED, SCOPE_AGENT);
    float t1 = __hip_atomic_load(&ca[tid + 256], __ATOMIC_RELAXED, SCOPE_AGENT);
    float d = fmaxf(fabsf(fmaf(t0, cl[tid], -1.0f)),
                    fabsf(fmaf(t1, cl[tid + 256], -1.0f)));
    #pragma unroll
    for (int off = 32; off >= 1; off >>= 1) d = fmaxf(d, __shfl_xor(d, off));
    if ((tid & 63) == 0) wmax[tid >> 6] = d;
    cl[tid] = 1.0f / t0; cl[tid + 256] = 1.0f / t1;
    __syncthreads();
    const float dm = fmaxf(fmaxf(wmax[0], wmax[1]), fmaxf(wmax[2], wmax[3]));
    convbit = (dm < 2e-3f) ? 1u : 0u;
    row_update();
  }

  // final: out = r_i * P0_ij * c_j   (float4, reads LDS only)
  float* Ob = out + ((size_t)b * NN + i0) * NN;
  #pragma unroll
  for (int rep = 0; rep < 8; ++rep) {
    const int row = rep * 2 + (tid >> 7);     // 0..15
    const int c4  = (tid & 127) * 4;          // 0..508
    const float rv = rl[row];
    float4 o;
    o.x = rv * Pl[row][c4 + 0] * cl[c4 + 0];
    o.y = rv * Pl[row][c4 + 1] * cl[c4 + 1];
    o.z = rv * Pl[row][c4 + 2] * cl[c4 + 2];
    o.w = rv * Pl[row][c4 + 3] * cl[c4 + 3];
    *reinterpret_cast<float4*>(&Ob[(size_t)row * NN + c4]) = o;
  }
}

// ------------------------------------------------------------- launch ------
extern "C" void kernel_launch(void* const* d_in, const int* in_sizes, int n_in,
                              void* d_out, int out_size, void* d_ws, size_t ws_size,
                              hipStream_t stream)
{
  const float* points = (const float*)d_in[0];
  const float* dist   = (const float*)d_in[1];
  const float* noise  = (const float*)d_in[2];
  const float* Wemb   = (const float*)d_in[3];
  const float* bemb   = (const float*)d_in[4];
  const float* W1 = (const float*)d_in[5]; const float* b1 = (const float*)d_in[6];
  const float* W2 = (const float*)d_in[7]; const float* b2 = (const float*)d_in[8];
  const float* W3 = (const float*)d_in[9]; const float* b3 = (const float*)d_in[10];
  float* out = (float*)d_out;

  char* ws = (char*)d_ws;                              // ws_size = 256 MiB
  _Float16* xfA = (_Float16*)ws;                       // 2 MB
  _Float16* xTA = (_Float16*)(ws + (2u << 20));        // 2 MB
  _Float16* xfB = (_Float16*)(ws + (4u << 20));        // 2 MB
  _Float16* xTB = (_Float16*)(ws + (6u << 20));        // 2 MB
  _Float16* adjw = (_Float16*)(ws + (8u << 20));       // 8 MB (f16 adjacency)
  char* ctrl = ws + (16u << 20);
  float*        cacc  = (float*)ctrl;                  // 64 KB
  unsigned int* flags = (unsigned int*)(ctrl + (64u << 10));  // 128 KB
  // ws usage: 16 MB + 192 KB << 256 MiB  ✓

  // 3 fused GCN layers, 512 blocks = 2/CU (layer 1 embeds on the fly,
  // writes adj16, zeroes ctrl)
  gcn_kernel<true><<<512, 256, 0, stream>>>(dist, adjw, nullptr, points, Wemb, bemb,
                                            W1, b1, xfA, xTA, (unsigned int*)ctrl);
  gcn_kernel<false><<<512, 256, 0, stream>>>(nullptr, adjw, xTA, nullptr, nullptr, nullptr,
                                             W2, b2, xfB, xTB, nullptr);
  gcn_kernel<false><<<512, 256, 0, stream>>>(nullptr, adjw, xTB, nullptr, nullptr, nullptr,
                                             W3, b3, xfA, xTA, nullptr);

  // Sinkhorn (logits fused in prologue; proven barrier protocol; eps=2e-3)
  const _Float16* xfc = xfA; const float* nzc = noise;
  float* caccP = cacc; unsigned int* flagsP = flags; float* outP = out;
  void* args[] = {(void*)&xfc, (void*)&nzc, (void*)&caccP, (void*)&flagsP, (void*)&outP};
  hipLaunchCooperativeKernel(reinterpret_cast<void*>(sinkhorn_kernel),
                             dim3(BB * SB), dim3(256), args, 0, stream);
}